// Round 8
// baseline (478.205 us; speedup 1.0000x reference)
//
#include <hip/hip_runtime.h>
#include <hip/hip_bf16.h>

typedef short bf16x8 __attribute__((ext_vector_type(8)));
typedef float f32x4 __attribute__((ext_vector_type(4)));
typedef float f32x16 __attribute__((ext_vector_type(16)));

#define NH 12
#define SEQ 1792
#define DMODEL 1536
#define HD 128

static __device__ __forceinline__ void gload16(const void* g, void* l) {
  __builtin_amdgcn_global_load_lds((const __attribute__((address_space(1))) void*)g,
                                   (__attribute__((address_space(3))) void*)l, 16, 0, 0);
}

static __device__ __forceinline__ short f2bf(float x) {
  __hip_bfloat16 h = __float2bfloat16(x);
  return *reinterpret_cast<short*>(&h);
}

static __device__ __forceinline__ unsigned pack2(float lo, float hi) {
  unsigned a = (unsigned)(unsigned short)f2bf(lo);
  unsigned b = (unsigned)(unsigned short)f2bf(hi);
  return a | (b << 16);
}

// ---------- fused fp32 -> bf16 cast for x + Wq + Wk + Wv + Wo (one launch) ----------
// chunk = 4 floats. Segments: x 2752512 | Wq/Wk/Wv/Wo 589824 each.
__global__ __launch_bounds__(256) void cast_all_kernel(
    const float* __restrict__ x, const float* __restrict__ wq, const float* __restrict__ wk,
    const float* __restrict__ wv, const float* __restrict__ wo,
    __hip_bfloat16* __restrict__ xb, __hip_bfloat16* __restrict__ wb,
    __hip_bfloat16* __restrict__ wob) {
  int i = blockIdx.x * 256 + threadIdx.x;
  const float* src; __hip_bfloat16* dst; int j;
  if (i < 2752512)      { src = x;  dst = xb;            j = i; }
  else if (i < 3342336) { src = wq; dst = wb;            j = i - 2752512; }
  else if (i < 3932160) { src = wk; dst = wb + 2359296;  j = i - 3342336; }
  else if (i < 4521984) { src = wv; dst = wb + 4718592;  j = i - 3932160; }
  else if (i < 5111808) { src = wo; dst = wob;           j = i - 4521984; }
  else return;
  float4 v = reinterpret_cast<const float4*>(src)[j];
  short4 r;
  r.x = f2bf(v.x); r.y = f2bf(v.y); r.z = f2bf(v.z); r.w = f2bf(v.w);
  reinterpret_cast<short4*>(dst)[j] = r;
}

// ---------- 128x128 bf16 GEMM, B^T layout (C = A @ B^T), m97 structure ----------
// MODE 0: QKV epilogue (bias + scatter q/k row-major per-head, v transposed)
// MODE 1: fp32 out epilogue (bias)
template<int MODE>
__global__ __launch_bounds__(256) void gemm_bt(
    const __hip_bfloat16* __restrict__ A, const __hip_bfloat16* __restrict__ B, int K,
    const float* __restrict__ bq, const float* __restrict__ bk, const float* __restrict__ bv,
    __hip_bfloat16* __restrict__ qbuf, __hip_bfloat16* __restrict__ kbuf,
    __hip_bfloat16* __restrict__ vt,
    const float* __restrict__ bo, float* __restrict__ outp)
{
  __shared__ __hip_bfloat16 Abuf[2][128 * 32];
  __shared__ __hip_bfloat16 Bbuf[2][128 * 32];
  const int tid = threadIdx.x;
  const int l = tid & 63, w = tid >> 6;
  const int lr = l & 15, lg = l >> 4;
  const int wr = w >> 1, wc = w & 1;
  const int m0 = blockIdx.y * 128, n0 = blockIdx.x * 128;
  const int nK = K >> 5;

  f32x4 acc[4][4] = {};

  auto stage = [&](int buf, int kk) {
#pragma unroll
    for (int q2 = 0; q2 < 2; ++q2) {
      int flat = q2 * 256 + tid;
      int row = flat >> 2;
      int kb16 = (flat & 3) * 16;
      const __hip_bfloat16* ga = A + (size_t)(m0 + row) * K + kk + (kb16 >> 1);
      gload16(ga, &Abuf[buf][(q2 * 256 + w * 64) * 8]);
      const __hip_bfloat16* gb = B + (size_t)(n0 + row) * K + kk + (kb16 >> 1);
      gload16(gb, &Bbuf[buf][(q2 * 256 + w * 64) * 8]);
    }
  };

  stage(0, 0);
  for (int kt = 0; kt < nK; ++kt) {
    __syncthreads();
    if (kt + 1 < nK) stage((kt + 1) & 1, (kt + 1) * 32);
    const __hip_bfloat16* Ab = Abuf[kt & 1];
    const __hip_bfloat16* Bb = Bbuf[kt & 1];
    bf16x8 af[4], bfr[4];
#pragma unroll
    for (int fi = 0; fi < 4; ++fi)
      af[fi] = *reinterpret_cast<const bf16x8*>(&Ab[(wr * 64 + fi * 16 + lr) * 32 + lg * 8]);
#pragma unroll
    for (int fj = 0; fj < 4; ++fj)
      bfr[fj] = *reinterpret_cast<const bf16x8*>(&Bb[(wc * 64 + fj * 16 + lr) * 32 + lg * 8]);
#pragma unroll
    for (int fi = 0; fi < 4; ++fi)
#pragma unroll
      for (int fj = 0; fj < 4; ++fj)
        acc[fi][fj] = __builtin_amdgcn_mfma_f32_16x16x32_bf16(af[fi], bfr[fj], acc[fi][fj], 0, 0, 0);
  }

  if (MODE == 0) {
#pragma unroll
    for (int fj = 0; fj < 4; ++fj) {
      int ncol = n0 + wc * 64 + fj * 16 + lr;
      int which = ncol / DMODEL;
      int cc = ncol - which * DMODEL;
      int hh = cc >> 7, dd = cc & 127;
      float bias = (which == 0 ? bq : which == 1 ? bk : bv)[cc];
#pragma unroll
      for (int fi = 0; fi < 4; ++fi)
#pragma unroll
        for (int r = 0; r < 4; ++r) {
          int rowg = m0 + wr * 64 + fi * 16 + lg * 4 + r;
          int bbb = rowg / SEQ;
          int sr = rowg - bbb * SEQ;
          __hip_bfloat16 hv = __float2bfloat16(acc[fi][fj][r] + bias);
          if (which == 0)
            qbuf[(((size_t)(bbb * NH + hh)) * SEQ + sr) * HD + dd] = hv;
          else if (which == 1)
            kbuf[(((size_t)(bbb * NH + hh)) * SEQ + sr) * HD + dd] = hv;
          else
            vt[(((size_t)(bbb * NH + hh)) * HD + dd) * SEQ + sr] = hv;
        }
    }
  } else {
#pragma unroll
    for (int fj = 0; fj < 4; ++fj) {
      int ncol = n0 + wc * 64 + fj * 16 + lr;
      float bias = bo[ncol];
#pragma unroll
      for (int fi = 0; fi < 4; ++fi)
#pragma unroll
        for (int r = 0; r < 4; ++r) {
          int rowg = m0 + wr * 64 + fi * 16 + lg * 4 + r;
          outp[(size_t)rowg * DMODEL + ncol] = acc[fi][fj][r] + bias;
        }
    }
  }
}

// ---------- RMSNorm (full-D) + 3D-grid RoPE, in-place on q,k ----------
// q additionally pre-scaled by 1/sqrt(HD) so attention skips the scale.
__global__ __launch_bounds__(256) void rmsrope_kernel(
    __hip_bfloat16* __restrict__ qb, __hip_bfloat16* __restrict__ kb,
    const float* __restrict__ gq, const float* __restrict__ gk,
    const float* __restrict__ fc, const float* __restrict__ fs,
    const int* __restrict__ gsz, const int* __restrict__ nmod)
{
  const int bs = blockIdx.x;
  const int b = bs / SEQ, s = bs - b * SEQ;
  const int t = threadIdx.x;
  const int f = gsz[0], h = gsz[1], wd = gsz[2];
  const int mm = nmod[0];
  const int seq_per = f * h * wd;
  int total_len = seq_per * mm; if (total_len > SEQ) total_len = SEQ;
  const bool dorope = s < total_len;
  int fi = 0, hi2 = 0, wi = 0;
  if (dorope) {
    int p = s % seq_per;
    fi = p / (h * wd);
    int rem = p - fi * (h * wd);
    hi2 = rem / wd;
    wi = rem - hi2 * wd;
  }
  float qv[3][2], kv[3][2];
  float sq = 0.f, sk = 0.f;
#pragma unroll
  for (int r = 0; r < 3; ++r) {
    int pi = t + r * 256;
    int head = pi >> 6;
    int dd = (pi & 63) * 2;
    size_t addr = (((size_t)(b * NH + head)) * SEQ + s) * HD + dd;
    __hip_bfloat162 q2 = *reinterpret_cast<const __hip_bfloat162*>(&qb[addr]);
    __hip_bfloat162 k2 = *reinterpret_cast<const __hip_bfloat162*>(&kb[addr]);
    qv[r][0] = __bfloat162float(q2.x); qv[r][1] = __bfloat162float(q2.y);
    kv[r][0] = __bfloat162float(k2.x); kv[r][1] = __bfloat162float(k2.y);
    sq += qv[r][0] * qv[r][0] + qv[r][1] * qv[r][1];
    sk += kv[r][0] * kv[r][0] + kv[r][1] * kv[r][1];
  }
#pragma unroll
  for (int off = 1; off < 64; off <<= 1) {
    sq += __shfl_xor(sq, off);
    sk += __shfl_xor(sk, off);
  }
  __shared__ float red[2][4];
  if ((t & 63) == 0) { red[0][t >> 6] = sq; red[1][t >> 6] = sk; }
  __syncthreads();
  float tq = red[0][0] + red[0][1] + red[0][2] + red[0][3];
  float tk = red[1][0] + red[1][1] + red[1][2] + red[1][3];
  float rq = rsqrtf(tq * (1.0f / DMODEL) + 1e-6f);
  float rk = rsqrtf(tk * (1.0f / DMODEL) + 1e-6f);
  const float scale = 0.08838834764831845f; // 1/sqrt(128), folded into q
#pragma unroll
  for (int r = 0; r < 3; ++r) {
    int pi = t + r * 256;
    int head = pi >> 6;
    int dd = (pi & 63) * 2;
    int col = pi * 2;
    size_t addr = (((size_t)(b * NH + head)) * SEQ + s) * HD + dd;
    float q0 = qv[r][0] * rq * gq[col], q1 = qv[r][1] * rq * gq[col + 1];
    float k0 = kv[r][0] * rk * gk[col], k1 = kv[r][1] * rk * gk[col + 1];
    if (dorope) {
      int j = pi & 63;
      int row = (j < 22) ? fi : (j < 43) ? hi2 : wi;
      float co = fc[row * 64 + j], si = fs[row * 64 + j];
      float a;
      a = q0 * co - q1 * si; q1 = q0 * si + q1 * co; q0 = a;
      a = k0 * co - k1 * si; k1 = k0 * si + k1 * co; k0 = a;
    }
    q0 *= scale; q1 *= scale;
    __hip_bfloat162 oq, ok;
    oq.x = __float2bfloat16(q0); oq.y = __float2bfloat16(q1);
    ok.x = __float2bfloat16(k0); ok.y = __float2bfloat16(k1);
    *reinterpret_cast<__hip_bfloat162*>(&qb[addr]) = oq;
    *reinterpret_cast<__hip_bfloat162*>(&kb[addr]) = ok;
  }
}

// ---------- flash attention v8: 4 waves x QBLK=32, 2-deep K dbuf, 3 blocks/CU ----------
// R6 structure (proven 209 us) + occupancy fix: __launch_bounds__(256,3) caps regs
// at 170 (need 172 -> ~2 rematerialized), LDS 32 KB -> 3 blocks/CU, grid 672 fits
// the 768 slots in ONE round (R6/R7 ran 1.31 rounds -> 24% tail waste).
__global__ __launch_bounds__(256, 3) void attn_kernel(
    const __hip_bfloat16* __restrict__ qb, const __hip_bfloat16* __restrict__ kbuf,
    const __hip_bfloat16* __restrict__ vt, const int* __restrict__ seq_lens,
    __hip_bfloat16* __restrict__ ob)
{
  const int orig = blockIdx.x;
  const int wg = (orig & 7) * 84 + (orig >> 3);
  const int bh = wg / 14, qt = wg % 14;
  const int bbb = bh / NH, hh = bh - bbb * NH;
  const int tid = threadIdx.x;
  const int w = tid >> 6, l = tid & 63;
  const int lq = l & 31, h = l >> 5;
  const int sl = seq_lens[bbb];
  const __hip_bfloat16* Q = qb + (size_t)bh * SEQ * HD;
  const char* Kc = (const char*)(kbuf + (size_t)bh * SEQ * HD);
  const __hip_bfloat16* Vp = vt + (size_t)bh * HD * SEQ;   // [128][1792]
  const int q0 = qt * 128 + w * 32;

  __shared__ __hip_bfloat16 Kt[2][64 * 128];   // 32 KB; byte ^= ((row&7)<<4)

  bf16x8 qf[8];
#pragma unroll
  for (int kc = 0; kc < 8; ++kc)
    qf[kc] = *reinterpret_cast<const bf16x8*>(
        &Q[(size_t)(q0 + lq) * HD + kc * 16 + h * 8]);

  f32x16 oacc[4] = {};                          // O[q_off][d0*32+lq]
  float m = -3e38f, ll = 0.f;                   // per-lane q-row softmax state

  const int nkt = (sl + 63) >> 6;

  auto stageK = [&](int buf, int k0) {
    char* Lb = (char*)&Kt[buf][0];
#pragma unroll
    for (int q2 = 0; q2 < 4; ++q2) {
      int chunk = q2 * 256 + tid;               // 16B chunk id in [0,1024)
      int row = chunk >> 4;                     // 16 chunks per 256B row
      int cb = (chunk & 15) << 4;
      int scb = cb ^ ((row & 7) << 4);          // inverse-swizzled source
      gload16(Kc + (size_t)(k0 + row) * 256 + scb, Lb + chunk * 16);
    }
  };

  stageK(0, 0);
  for (int kt = 0; kt < nkt; ++kt) {
    __syncthreads();                            // stage(kt) drained; prev compute done
    const int k0 = kt * 64;
    if (kt + 1 < nkt) stageK((kt + 1) & 1, k0 + 64);
    const char* Kl = (const char*)&Kt[kt & 1][0];

    // swapped QK^T: S^T[k][q], 16 ds_read_b128 + 16 mfma_32x32x16
    f32x16 sa[2] = {};
#pragma unroll
    for (int cb = 0; cb < 2; ++cb) {
      int row = cb * 32 + lq;
      int swz = (row & 7) << 4;
#pragma unroll
      for (int kc = 0; kc < 8; ++kc) {
        bf16x8 kf = *reinterpret_cast<const bf16x8*>(
            Kl + row * 256 + ((kc * 32 + h * 16) ^ swz));
        sa[cb] = __builtin_amdgcn_mfma_f32_32x32x16_bf16(kf, qf[kc], sa[cb], 0, 0, 0);
      }
    }

    // mask tail (rare): k of sa[cb][r] = k0 + cb*32 + (r&3) + 8*(r>>2) + 4*h
    if (k0 + 64 > sl) {
#pragma unroll
      for (int cb = 0; cb < 2; ++cb)
#pragma unroll
        for (int r = 0; r < 16; ++r) {
          int kg = k0 + cb * 32 + (r & 3) + 8 * (r >> 2) + 4 * h;
          if (kg >= sl) sa[cb][r] = -3e38f;
        }
    }

    // in-register online softmax: lane owns q-row (lq), halves split across h
    float mx = -3e38f;
#pragma unroll
    for (int cb = 0; cb < 2; ++cb)
#pragma unroll
      for (int r = 0; r < 16; ++r) mx = fmaxf(mx, sa[cb][r]);
    mx = fmaxf(mx, __shfl_xor(mx, 32));

    if (__any(mx - m > 8.f)) {                  // defer-max (T13)
      float mn = fmaxf(m, mx);
      float alpha = __expf(m - mn);
      m = mn;
      ll *= alpha;
#pragma unroll
      for (int r = 0; r < 16; ++r) {
        float ar = __shfl(alpha, (r & 3) + 8 * (r >> 2) + 4 * h);
#pragma unroll
        for (int d0 = 0; d0 < 4; ++d0) oacc[d0][r] *= ar;
      }
    }

    float rs = 0.f;
#pragma unroll
    for (int cb = 0; cb < 2; ++cb)
#pragma unroll
      for (int r = 0; r < 16; ++r) {
        float e = __expf(sa[cb][r] - m);
        sa[cb][r] = e;
        rs += e;
      }
    rs += __shfl_xor(rs, 32);
    ll += rs;

    // P -> bf16 A-frags (pack + shfl_xor(32) exchange) and PV
#pragma unroll
    for (int c = 0; c < 4; ++c) {
      const int cb = c >> 1, r0 = 8 * (c & 1);
      unsigned A01 = pack2(sa[cb][r0],     sa[cb][r0 + 1]);
      unsigned A23 = pack2(sa[cb][r0 + 2], sa[cb][r0 + 3]);
      unsigned B01 = pack2(sa[cb][r0 + 4], sa[cb][r0 + 5]);
      unsigned B23 = pack2(sa[cb][r0 + 6], sa[cb][r0 + 7]);
      unsigned s1 = __shfl_xor(h ? A01 : B01, 32);
      unsigned s2 = __shfl_xor(h ? A23 : B23, 32);
      int4 wv;
      wv.x = (int)(h ? s1 : A01);
      wv.y = (int)(h ? s2 : A23);
      wv.z = (int)(h ? B01 : s1);
      wv.w = (int)(h ? B23 : s2);
      bf16x8 pa = *reinterpret_cast<bf16x8*>(&wv);
#pragma unroll
      for (int d0 = 0; d0 < 4; ++d0) {
        bf16x8 vv = *reinterpret_cast<const bf16x8*>(
            &Vp[(size_t)(d0 * 32 + lq) * SEQ + k0 + c * 16 + h * 8]);
        oacc[d0] = __builtin_amdgcn_mfma_f32_32x32x16_bf16(pa, vv, oacc[d0], 0, 0, 0);
      }
    }
  }

  // epilogue: normalize by per-q-row sum, write O
  float invl = 1.0f / ll;
#pragma unroll
  for (int r = 0; r < 16; ++r) {
    int qoff = (r & 3) + 8 * (r >> 2) + 4 * h;
    float ir = __shfl(invl, qoff);
    int qrow = q0 + qoff;
#pragma unroll
    for (int d0 = 0; d0 < 4; ++d0)
      ob[((size_t)bbb * SEQ + qrow) * DMODEL + hh * HD + d0 * 32 + lq] =
          __float2bfloat16(oacc[d0][r] * ir);
  }
}

// ---------- launch ----------
extern "C" void kernel_launch(void* const* d_in, const int* in_sizes, int n_in,
                              void* d_out, int out_size, void* d_ws, size_t ws_size,
                              hipStream_t stream) {
  const float* x   = (const float*)d_in[0];
  const int* seq_lens   = (const int*)d_in[1];
  const int* grid_sizes = (const int*)d_in[2];
  const float* fc  = (const float*)d_in[3];
  const float* fs  = (const float*)d_in[4];
  const float* Wq  = (const float*)d_in[5];
  const float* bq  = (const float*)d_in[6];
  const float* Wk  = (const float*)d_in[7];
  const float* bk  = (const float*)d_in[8];
  const float* Wv  = (const float*)d_in[9];
  const float* bv  = (const float*)d_in[10];
  const float* Wo  = (const float*)d_in[11];
  const float* bo  = (const float*)d_in[12];
  const float* gq  = (const float*)d_in[13];
  const float* gk  = (const float*)d_in[14];
  const int* nmod  = (const int*)d_in[15];
  float* out = (float*)d_out;

  char* ws = (char*)d_ws;
  __hip_bfloat16* xb   = (__hip_bfloat16*)(ws + 0);           // [7168][1536]
  __hip_bfloat16* wb   = (__hip_bfloat16*)(ws + 22020096);    // [4608][1536]
  __hip_bfloat16* wob  = (__hip_bfloat16*)(ws + 36175872);    // [1536][1536]
  __hip_bfloat16* qbuf = (__hip_bfloat16*)(ws + 40894464);    // [48][1792][128]
  __hip_bfloat16* kbuf = (__hip_bfloat16*)(ws + 62914560);    // [48][1792][128]
  __hip_bfloat16* vtb  = (__hip_bfloat16*)(ws + 84934656);    // [48][128][1792]
  __hip_bfloat16* ob   = xb;                                  // O reuses xb region

  cast_all_kernel<<<(5111808 + 255) / 256, 256, 0, stream>>>(x, Wq, Wk, Wv, Wo, xb, wb, wob);

  gemm_bt<0><<<dim3(36, 56), 256, 0, stream>>>(xb, wb, 1536, bq, bk, bv,
                                               qbuf, kbuf, vtb, nullptr, nullptr);
  rmsrope_kernel<<<7168, 256, 0, stream>>>(qbuf, kbuf, gq, gk, fc, fs, grid_sizes, nmod);
  attn_kernel<<<672, 256, 0, stream>>>(qbuf, kbuf, vtb, seq_lens, ob);
  gemm_bt<1><<<dim3(12, 56), 256, 0, stream>>>(ob, wob, 1536, nullptr, nullptr, nullptr,
                                               nullptr, nullptr, nullptr, bo, out);
}

// Round 9
// 458.024 us; speedup vs baseline: 1.0441x; 1.0441x over previous
//
#include <hip/hip_runtime.h>
#include <hip/hip_bf16.h>

typedef short bf16x8 __attribute__((ext_vector_type(8)));
typedef float f32x4 __attribute__((ext_vector_type(4)));
typedef float f32x16 __attribute__((ext_vector_type(16)));

#define NH 12
#define SEQ 1792
#define DMODEL 1536
#define HD 128

static __device__ __forceinline__ void gload16(const void* g, void* l) {
  __builtin_amdgcn_global_load_lds((const __attribute__((address_space(1))) void*)g,
                                   (__attribute__((address_space(3))) void*)l, 16, 0, 0);
}

static __device__ __forceinline__ short f2bf(float x) {
  __hip_bfloat16 h = __float2bfloat16(x);
  return *reinterpret_cast<short*>(&h);
}

static __device__ __forceinline__ unsigned pack2(float lo, float hi) {
  unsigned a = (unsigned)(unsigned short)f2bf(lo);
  unsigned b = (unsigned)(unsigned short)f2bf(hi);
  return a | (b << 16);
}

// ---------- fused fp32 -> bf16 cast for x + Wq + Wk + Wv + Wo (one launch) ----------
__global__ __launch_bounds__(256) void cast_all_kernel(
    const float* __restrict__ x, const float* __restrict__ wq, const float* __restrict__ wk,
    const float* __restrict__ wv, const float* __restrict__ wo,
    __hip_bfloat16* __restrict__ xb, __hip_bfloat16* __restrict__ wb,
    __hip_bfloat16* __restrict__ wob) {
  int i = blockIdx.x * 256 + threadIdx.x;
  const float* src; __hip_bfloat16* dst; int j;
  if (i < 2752512)      { src = x;  dst = xb;            j = i; }
  else if (i < 3342336) { src = wq; dst = wb;            j = i - 2752512; }
  else if (i < 3932160) { src = wk; dst = wb + 2359296;  j = i - 3342336; }
  else if (i < 4521984) { src = wv; dst = wb + 4718592;  j = i - 3932160; }
  else if (i < 5111808) { src = wo; dst = wob;           j = i - 4521984; }
  else return;
  float4 v = reinterpret_cast<const float4*>(src)[j];
  short4 r;
  r.x = f2bf(v.x); r.y = f2bf(v.y); r.z = f2bf(v.z); r.w = f2bf(v.w);
  reinterpret_cast<short4*>(dst)[j] = r;
}

// ---------- 128x128 bf16 GEMM, B^T layout (C = A @ B^T), m97 structure ----------
template<int MODE>
__global__ __launch_bounds__(256) void gemm_bt(
    const __hip_bfloat16* __restrict__ A, const __hip_bfloat16* __restrict__ B, int K,
    const float* __restrict__ bq, const float* __restrict__ bk, const float* __restrict__ bv,
    __hip_bfloat16* __restrict__ qbuf, __hip_bfloat16* __restrict__ kbuf,
    __hip_bfloat16* __restrict__ vt,
    const float* __restrict__ bo, float* __restrict__ outp)
{
  __shared__ __hip_bfloat16 Abuf[2][128 * 32];
  __shared__ __hip_bfloat16 Bbuf[2][128 * 32];
  const int tid = threadIdx.x;
  const int l = tid & 63, w = tid >> 6;
  const int lr = l & 15, lg = l >> 4;
  const int wr = w >> 1, wc = w & 1;
  const int m0 = blockIdx.y * 128, n0 = blockIdx.x * 128;
  const int nK = K >> 5;

  f32x4 acc[4][4] = {};

  auto stage = [&](int buf, int kk) {
#pragma unroll
    for (int q2 = 0; q2 < 2; ++q2) {
      int flat = q2 * 256 + tid;
      int row = flat >> 2;
      int kb16 = (flat & 3) * 16;
      const __hip_bfloat16* ga = A + (size_t)(m0 + row) * K + kk + (kb16 >> 1);
      gload16(ga, &Abuf[buf][(q2 * 256 + w * 64) * 8]);
      const __hip_bfloat16* gb = B + (size_t)(n0 + row) * K + kk + (kb16 >> 1);
      gload16(gb, &Bbuf[buf][(q2 * 256 + w * 64) * 8]);
    }
  };

  stage(0, 0);
  for (int kt = 0; kt < nK; ++kt) {
    __syncthreads();
    if (kt + 1 < nK) stage((kt + 1) & 1, (kt + 1) * 32);
    const __hip_bfloat16* Ab = Abuf[kt & 1];
    const __hip_bfloat16* Bb = Bbuf[kt & 1];
    bf16x8 af[4], bfr[4];
#pragma unroll
    for (int fi = 0; fi < 4; ++fi)
      af[fi] = *reinterpret_cast<const bf16x8*>(&Ab[(wr * 64 + fi * 16 + lr) * 32 + lg * 8]);
#pragma unroll
    for (int fj = 0; fj < 4; ++fj)
      bfr[fj] = *reinterpret_cast<const bf16x8*>(&Bb[(wc * 64 + fj * 16 + lr) * 32 + lg * 8]);
#pragma unroll
    for (int fi = 0; fi < 4; ++fi)
#pragma unroll
      for (int fj = 0; fj < 4; ++fj)
        acc[fi][fj] = __builtin_amdgcn_mfma_f32_16x16x32_bf16(af[fi], bfr[fj], acc[fi][fj], 0, 0, 0);
  }

  if (MODE == 0) {
#pragma unroll
    for (int fj = 0; fj < 4; ++fj) {
      int ncol = n0 + wc * 64 + fj * 16 + lr;
      int which = ncol / DMODEL;
      int cc = ncol - which * DMODEL;
      int hh = cc >> 7, dd = cc & 127;
      float bias = (which == 0 ? bq : which == 1 ? bk : bv)[cc];
#pragma unroll
      for (int fi = 0; fi < 4; ++fi)
#pragma unroll
        for (int r = 0; r < 4; ++r) {
          int rowg = m0 + wr * 64 + fi * 16 + lg * 4 + r;
          int bbb = rowg / SEQ;
          int sr = rowg - bbb * SEQ;
          __hip_bfloat16 hv = __float2bfloat16(acc[fi][fj][r] + bias);
          if (which == 0)
            qbuf[(((size_t)(bbb * NH + hh)) * SEQ + sr) * HD + dd] = hv;
          else if (which == 1)
            kbuf[(((size_t)(bbb * NH + hh)) * SEQ + sr) * HD + dd] = hv;
          else
            vt[(((size_t)(bbb * NH + hh)) * HD + dd) * SEQ + sr] = hv;
        }
    }
  } else {
#pragma unroll
    for (int fj = 0; fj < 4; ++fj) {
      int ncol = n0 + wc * 64 + fj * 16 + lr;
      float bias = bo[ncol];
#pragma unroll
      for (int fi = 0; fi < 4; ++fi)
#pragma unroll
        for (int r = 0; r < 4; ++r) {
          int rowg = m0 + wr * 64 + fi * 16 + lg * 4 + r;
          outp[(size_t)rowg * DMODEL + ncol] = acc[fi][fj][r] + bias;
        }
    }
  }
}

// ---------- RMSNorm (full-D) + 3D-grid RoPE, in-place on q,k ----------
__global__ __launch_bounds__(256) void rmsrope_kernel(
    __hip_bfloat16* __restrict__ qb, __hip_bfloat16* __restrict__ kb,
    const float* __restrict__ gq, const float* __restrict__ gk,
    const float* __restrict__ fc, const float* __restrict__ fs,
    const int* __restrict__ gsz, const int* __restrict__ nmod)
{
  const int bs = blockIdx.x;
  const int b = bs / SEQ, s = bs - b * SEQ;
  const int t = threadIdx.x;
  const int f = gsz[0], h = gsz[1], wd = gsz[2];
  const int mm = nmod[0];
  const int seq_per = f * h * wd;
  int total_len = seq_per * mm; if (total_len > SEQ) total_len = SEQ;
  const bool dorope = s < total_len;
  int fi = 0, hi2 = 0, wi = 0;
  if (dorope) {
    int p = s % seq_per;
    fi = p / (h * wd);
    int rem = p - fi * (h * wd);
    hi2 = rem / wd;
    wi = rem - hi2 * wd;
  }
  float qv[3][2], kv[3][2];
  float sq = 0.f, sk = 0.f;
#pragma unroll
  for (int r = 0; r < 3; ++r) {
    int pi = t + r * 256;
    int head = pi >> 6;
    int dd = (pi & 63) * 2;
    size_t addr = (((size_t)(b * NH + head)) * SEQ + s) * HD + dd;
    __hip_bfloat162 q2 = *reinterpret_cast<const __hip_bfloat162*>(&qb[addr]);
    __hip_bfloat162 k2 = *reinterpret_cast<const __hip_bfloat162*>(&kb[addr]);
    qv[r][0] = __bfloat162float(q2.x); qv[r][1] = __bfloat162float(q2.y);
    kv[r][0] = __bfloat162float(k2.x); kv[r][1] = __bfloat162float(k2.y);
    sq += qv[r][0] * qv[r][0] + qv[r][1] * qv[r][1];
    sk += kv[r][0] * kv[r][0] + kv[r][1] * kv[r][1];
  }
#pragma unroll
  for (int off = 1; off < 64; off <<= 1) {
    sq += __shfl_xor(sq, off);
    sk += __shfl_xor(sk, off);
  }
  __shared__ float red[2][4];
  if ((t & 63) == 0) { red[0][t >> 6] = sq; red[1][t >> 6] = sk; }
  __syncthreads();
  float tq = red[0][0] + red[0][1] + red[0][2] + red[0][3];
  float tk = red[1][0] + red[1][1] + red[1][2] + red[1][3];
  float rq = rsqrtf(tq * (1.0f / DMODEL) + 1e-6f);
  float rk = rsqrtf(tk * (1.0f / DMODEL) + 1e-6f);
  const float scale = 0.08838834764831845f; // 1/sqrt(128), folded into q
#pragma unroll
  for (int r = 0; r < 3; ++r) {
    int pi = t + r * 256;
    int head = pi >> 6;
    int dd = (pi & 63) * 2;
    int col = pi * 2;
    size_t addr = (((size_t)(b * NH + head)) * SEQ + s) * HD + dd;
    float q0 = qv[r][0] * rq * gq[col], q1 = qv[r][1] * rq * gq[col + 1];
    float k0 = kv[r][0] * rk * gk[col], k1 = kv[r][1] * rk * gk[col + 1];
    if (dorope) {
      int j = pi & 63;
      int row = (j < 22) ? fi : (j < 43) ? hi2 : wi;
      float co = fc[row * 64 + j], si = fs[row * 64 + j];
      float a;
      a = q0 * co - q1 * si; q1 = q0 * si + q1 * co; q0 = a;
      a = k0 * co - k1 * si; k1 = k0 * si + k1 * co; k0 = a;
    }
    q0 *= scale; q1 *= scale;
    __hip_bfloat162 oq, ok;
    oq.x = __float2bfloat16(q0); oq.y = __float2bfloat16(q1);
    ok.x = __float2bfloat16(k0); ok.y = __float2bfloat16(k1);
    *reinterpret_cast<__hip_bfloat162*>(&qb[addr]) = oq;
    *reinterpret_cast<__hip_bfloat162*>(&kb[addr]) = ok;
  }
}

// ---------- flash attention v9: 4 waves x QBLK=32, K LDS dbuf, V issue-early ----------
// R6 structure + T14: all 16 V b128 loads for tile kt issued at the TOP of the
// tile body (right after the barrier), consumed by PV ~QK^T+softmax later --
// hides the ~200-500cy L1/L2 latency that R8 showed occupancy can't cover.
// Costs +64 VGPR -> (256,2); R8 proved 2 vs 3 blocks/CU is perf-neutral.
__global__ __launch_bounds__(256, 2) void attn_kernel(
    const __hip_bfloat16* __restrict__ qb, const __hip_bfloat16* __restrict__ kbuf,
    const __hip_bfloat16* __restrict__ vt, const int* __restrict__ seq_lens,
    __hip_bfloat16* __restrict__ ob)
{
  const int orig = blockIdx.x;
  const int wg = (orig & 7) * 84 + (orig >> 3);
  const int bh = wg / 14, qt = wg % 14;
  const int bbb = bh / NH, hh = bh - bbb * NH;
  const int tid = threadIdx.x;
  const int w = tid >> 6, l = tid & 63;
  const int lq = l & 31, h = l >> 5;
  const int sl = seq_lens[bbb];
  const __hip_bfloat16* Q = qb + (size_t)bh * SEQ * HD;
  const char* Kc = (const char*)(kbuf + (size_t)bh * SEQ * HD);
  const __hip_bfloat16* Vp = vt + (size_t)bh * HD * SEQ;   // [128][1792]
  const int q0 = qt * 128 + w * 32;

  __shared__ __hip_bfloat16 Kt[2][64 * 128];   // 32 KB; byte ^= ((row&7)<<4)

  bf16x8 qf[8];
#pragma unroll
  for (int kc = 0; kc < 8; ++kc)
    qf[kc] = *reinterpret_cast<const bf16x8*>(
        &Q[(size_t)(q0 + lq) * HD + kc * 16 + h * 8]);

  // per-lane V row bases (row = d0*32+lq, byte col h*16 within 16B chunk pattern)
  const __hip_bfloat16* vrow[4];
#pragma unroll
  for (int d0 = 0; d0 < 4; ++d0)
    vrow[d0] = Vp + (size_t)(d0 * 32 + lq) * SEQ + h * 8;

  f32x16 oacc[4] = {};                          // O[q_off][d0*32+lq]
  float m = -3e38f, ll = 0.f;                   // per-lane q-row softmax state

  const int nkt = (sl + 63) >> 6;

  auto stageK = [&](int buf, int k0) {
    char* Lb = (char*)&Kt[buf][0];
#pragma unroll
    for (int q2 = 0; q2 < 4; ++q2) {
      int chunk = q2 * 256 + tid;               // 16B chunk id in [0,1024)
      int row = chunk >> 4;                     // 16 chunks per 256B row
      int cb = (chunk & 15) << 4;
      int scb = cb ^ ((row & 7) << 4);          // inverse-swizzled source
      gload16(Kc + (size_t)(k0 + row) * 256 + scb, Lb + chunk * 16);
    }
  };

  stageK(0, 0);
  for (int kt = 0; kt < nkt; ++kt) {
    __syncthreads();                            // stage(kt) drained; prev compute done
    const int k0 = kt * 64;
    if (kt + 1 < nkt) stageK((kt + 1) & 1, k0 + 64);

    // T14 issue-early: all 16 V fragments for THIS tile, consumed at PV below.
    bf16x8 vv[4][4];                            // [c][d0]
#pragma unroll
    for (int c = 0; c < 4; ++c)
#pragma unroll
      for (int d0 = 0; d0 < 4; ++d0)
        vv[c][d0] = *reinterpret_cast<const bf16x8*>(vrow[d0] + k0 + c * 16);

    const char* Kl = (const char*)&Kt[kt & 1][0];

    // swapped QK^T: S^T[k][q], 16 ds_read_b128 + 16 mfma_32x32x16
    f32x16 sa[2] = {};
#pragma unroll
    for (int cb = 0; cb < 2; ++cb) {
      int row = cb * 32 + lq;
      int swz = (row & 7) << 4;
#pragma unroll
      for (int kc = 0; kc < 8; ++kc) {
        bf16x8 kf = *reinterpret_cast<const bf16x8*>(
            Kl + row * 256 + ((kc * 32 + h * 16) ^ swz));
        sa[cb] = __builtin_amdgcn_mfma_f32_32x32x16_bf16(kf, qf[kc], sa[cb], 0, 0, 0);
      }
    }

    // mask tail (rare): k of sa[cb][r] = k0 + cb*32 + (r&3) + 8*(r>>2) + 4*h
    if (k0 + 64 > sl) {
#pragma unroll
      for (int cb = 0; cb < 2; ++cb)
#pragma unroll
        for (int r = 0; r < 16; ++r) {
          int kg = k0 + cb * 32 + (r & 3) + 8 * (r >> 2) + 4 * h;
          if (kg >= sl) sa[cb][r] = -3e38f;
        }
    }

    // in-register online softmax: lane owns q-row (lq), halves split across h
    float mx = -3e38f;
#pragma unroll
    for (int cb = 0; cb < 2; ++cb)
#pragma unroll
      for (int r = 0; r < 16; ++r) mx = fmaxf(mx, sa[cb][r]);
    mx = fmaxf(mx, __shfl_xor(mx, 32));

    if (__any(mx - m > 8.f)) {                  // defer-max (T13)
      float mn = fmaxf(m, mx);
      float alpha = __expf(m - mn);
      m = mn;
      ll *= alpha;
#pragma unroll
      for (int r = 0; r < 16; ++r) {
        float ar = __shfl(alpha, (r & 3) + 8 * (r >> 2) + 4 * h);
#pragma unroll
        for (int d0 = 0; d0 < 4; ++d0) oacc[d0][r] *= ar;
      }
    }

    float rs = 0.f;
#pragma unroll
    for (int cb = 0; cb < 2; ++cb)
#pragma unroll
      for (int r = 0; r < 16; ++r) {
        float e = __expf(sa[cb][r] - m);
        sa[cb][r] = e;
        rs += e;
      }
    rs += __shfl_xor(rs, 32);
    ll += rs;

    // P -> bf16 A-frags (pack + shfl_xor(32) exchange) and PV (V from registers)
#pragma unroll
    for (int c = 0; c < 4; ++c) {
      const int cb = c >> 1, r0 = 8 * (c & 1);
      unsigned A01 = pack2(sa[cb][r0],     sa[cb][r0 + 1]);
      unsigned A23 = pack2(sa[cb][r0 + 2], sa[cb][r0 + 3]);
      unsigned B01 = pack2(sa[cb][r0 + 4], sa[cb][r0 + 5]);
      unsigned B23 = pack2(sa[cb][r0 + 6], sa[cb][r0 + 7]);
      unsigned s1 = __shfl_xor(h ? A01 : B01, 32);
      unsigned s2 = __shfl_xor(h ? A23 : B23, 32);
      int4 wv;
      wv.x = (int)(h ? s1 : A01);
      wv.y = (int)(h ? s2 : A23);
      wv.z = (int)(h ? B01 : s1);
      wv.w = (int)(h ? B23 : s2);
      bf16x8 pa = *reinterpret_cast<bf16x8*>(&wv);
#pragma unroll
      for (int d0 = 0; d0 < 4; ++d0)
        oacc[d0] = __builtin_amdgcn_mfma_f32_32x32x16_bf16(pa, vv[c][d0], oacc[d0], 0, 0, 0);
    }
  }

  // epilogue: normalize by per-q-row sum, write O
  float invl = 1.0f / ll;
#pragma unroll
  for (int r = 0; r < 16; ++r) {
    int qoff = (r & 3) + 8 * (r >> 2) + 4 * h;
    float ir = __shfl(invl, qoff);
    int qrow = q0 + qoff;
#pragma unroll
    for (int d0 = 0; d0 < 4; ++d0)
      ob[((size_t)bbb * SEQ + qrow) * DMODEL + hh * HD + d0 * 32 + lq] =
          __float2bfloat16(oacc[d0][r] * ir);
  }
}

// ---------- launch ----------
extern "C" void kernel_launch(void* const* d_in, const int* in_sizes, int n_in,
                              void* d_out, int out_size, void* d_ws, size_t ws_size,
                              hipStream_t stream) {
  const float* x   = (const float*)d_in[0];
  const int* seq_lens   = (const int*)d_in[1];
  const int* grid_sizes = (const int*)d_in[2];
  const float* fc  = (const float*)d_in[3];
  const float* fs  = (const float*)d_in[4];
  const float* Wq  = (const float*)d_in[5];
  const float* bq  = (const float*)d_in[6];
  const float* Wk  = (const float*)d_in[7];
  const float* bk  = (const float*)d_in[8];
  const float* Wv  = (const float*)d_in[9];
  const float* bv  = (const float*)d_in[10];
  const float* Wo  = (const float*)d_in[11];
  const float* bo  = (const float*)d_in[12];
  const float* gq  = (const float*)d_in[13];
  const float* gk  = (const float*)d_in[14];
  const int* nmod  = (const int*)d_in[15];
  float* out = (float*)d_out;

  char* ws = (char*)d_ws;
  __hip_bfloat16* xb   = (__hip_bfloat16*)(ws + 0);           // [7168][1536]
  __hip_bfloat16* wb   = (__hip_bfloat16*)(ws + 22020096);    // [4608][1536]
  __hip_bfloat16* wob  = (__hip_bfloat16*)(ws + 36175872);    // [1536][1536]
  __hip_bfloat16* qbuf = (__hip_bfloat16*)(ws + 40894464);    // [48][1792][128]
  __hip_bfloat16* kbuf = (__hip_bfloat16*)(ws + 62914560);    // [48][1792][128]
  __hip_bfloat16* vtb  = (__hip_bfloat16*)(ws + 84934656);    // [48][128][1792]
  __hip_bfloat16* ob   = xb;                                  // O reuses xb region

  cast_all_kernel<<<(5111808 + 255) / 256, 256, 0, stream>>>(x, Wq, Wk, Wv, Wo, xb, wb, wob);

  gemm_bt<0><<<dim3(36, 56), 256, 0, stream>>>(xb, wb, 1536, bq, bk, bv,
                                               qbuf, kbuf, vtb, nullptr, nullptr);
  rmsrope_kernel<<<7168, 256, 0, stream>>>(qbuf, kbuf, gq, gk, fc, fs, grid_sizes, nmod);
  attn_kernel<<<672, 256, 0, stream>>>(qbuf, kbuf, vtb, seq_lens, ob);
  gemm_bt<1><<<dim3(12, 56), 256, 0, stream>>>(ob, wob, 1536, nullptr, nullptr, nullptr,
                                               nullptr, nullptr, nullptr, bo, out);
}

// Round 10
// 390.046 us; speedup vs baseline: 1.2260x; 1.1743x over previous
//
#include <hip/hip_runtime.h>
#include <hip/hip_bf16.h>

typedef short bf16x8 __attribute__((ext_vector_type(8)));
typedef float f32x4 __attribute__((ext_vector_type(4)));
typedef float f32x16 __attribute__((ext_vector_type(16)));

#define NH 12
#define SEQ 1792
#define DMODEL 1536
#define HD 128

static __device__ __forceinline__ void gload16(const void* g, void* l) {
  __builtin_amdgcn_global_load_lds((const __attribute__((address_space(1))) void*)g,
                                   (__attribute__((address_space(3))) void*)l, 16, 0, 0);
}

static __device__ __forceinline__ short f2bf(float x) {
  __hip_bfloat16 h = __float2bfloat16(x);
  return *reinterpret_cast<short*>(&h);
}

static __device__ __forceinline__ unsigned pack2(float lo, float hi) {
  unsigned a = (unsigned)(unsigned short)f2bf(lo);
  unsigned b = (unsigned)(unsigned short)f2bf(hi);
  return a | (b << 16);
}

// ---------- fused fp32 -> bf16 cast for x + Wq + Wk + Wv + Wo (one launch) ----------
__global__ __launch_bounds__(256) void cast_all_kernel(
    const float* __restrict__ x, const float* __restrict__ wq, const float* __restrict__ wk,
    const float* __restrict__ wv, const float* __restrict__ wo,
    __hip_bfloat16* __restrict__ xb, __hip_bfloat16* __restrict__ wb,
    __hip_bfloat16* __restrict__ wob) {
  int i = blockIdx.x * 256 + threadIdx.x;
  const float* src; __hip_bfloat16* dst; int j;
  if (i < 2752512)      { src = x;  dst = xb;            j = i; }
  else if (i < 3342336) { src = wq; dst = wb;            j = i - 2752512; }
  else if (i < 3932160) { src = wk; dst = wb + 2359296;  j = i - 3342336; }
  else if (i < 4521984) { src = wv; dst = wb + 4718592;  j = i - 3932160; }
  else if (i < 5111808) { src = wo; dst = wob;           j = i - 4521984; }
  else return;
  float4 v = reinterpret_cast<const float4*>(src)[j];
  short4 r;
  r.x = f2bf(v.x); r.y = f2bf(v.y); r.z = f2bf(v.z); r.w = f2bf(v.w);
  reinterpret_cast<short4*>(dst)[j] = r;
}

// ---------- 128x128 bf16 GEMM, B^T layout (C = A @ B^T), m97 structure ----------
template<int MODE>
__global__ __launch_bounds__(256) void gemm_bt(
    const __hip_bfloat16* __restrict__ A, const __hip_bfloat16* __restrict__ B, int K,
    const float* __restrict__ bq, const float* __restrict__ bk, const float* __restrict__ bv,
    __hip_bfloat16* __restrict__ qbuf, __hip_bfloat16* __restrict__ kbuf,
    __hip_bfloat16* __restrict__ vt,
    const float* __restrict__ bo, float* __restrict__ outp)
{
  __shared__ __hip_bfloat16 Abuf[2][128 * 32];
  __shared__ __hip_bfloat16 Bbuf[2][128 * 32];
  const int tid = threadIdx.x;
  const int l = tid & 63, w = tid >> 6;
  const int lr = l & 15, lg = l >> 4;
  const int wr = w >> 1, wc = w & 1;
  const int m0 = blockIdx.y * 128, n0 = blockIdx.x * 128;
  const int nK = K >> 5;

  f32x4 acc[4][4] = {};

  auto stage = [&](int buf, int kk) {
#pragma unroll
    for (int q2 = 0; q2 < 2; ++q2) {
      int flat = q2 * 256 + tid;
      int row = flat >> 2;
      int kb16 = (flat & 3) * 16;
      const __hip_bfloat16* ga = A + (size_t)(m0 + row) * K + kk + (kb16 >> 1);
      gload16(ga, &Abuf[buf][(q2 * 256 + w * 64) * 8]);
      const __hip_bfloat16* gb = B + (size_t)(n0 + row) * K + kk + (kb16 >> 1);
      gload16(gb, &Bbuf[buf][(q2 * 256 + w * 64) * 8]);
    }
  };

  stage(0, 0);
  for (int kt = 0; kt < nK; ++kt) {
    __syncthreads();
    if (kt + 1 < nK) stage((kt + 1) & 1, (kt + 1) * 32);
    const __hip_bfloat16* Ab = Abuf[kt & 1];
    const __hip_bfloat16* Bb = Bbuf[kt & 1];
    bf16x8 af[4], bfr[4];
#pragma unroll
    for (int fi = 0; fi < 4; ++fi)
      af[fi] = *reinterpret_cast<const bf16x8*>(&Ab[(wr * 64 + fi * 16 + lr) * 32 + lg * 8]);
#pragma unroll
    for (int fj = 0; fj < 4; ++fj)
      bfr[fj] = *reinterpret_cast<const bf16x8*>(&Bb[(wc * 64 + fj * 16 + lr) * 32 + lg * 8]);
#pragma unroll
    for (int fi = 0; fi < 4; ++fi)
#pragma unroll
      for (int fj = 0; fj < 4; ++fj)
        acc[fi][fj] = __builtin_amdgcn_mfma_f32_16x16x32_bf16(af[fi], bfr[fj], acc[fi][fj], 0, 0, 0);
  }

  if (MODE == 0) {
#pragma unroll
    for (int fj = 0; fj < 4; ++fj) {
      int ncol = n0 + wc * 64 + fj * 16 + lr;
      int which = ncol / DMODEL;
      int cc = ncol - which * DMODEL;
      int hh = cc >> 7, dd = cc & 127;
      float bias = (which == 0 ? bq : which == 1 ? bk : bv)[cc];
#pragma unroll
      for (int fi = 0; fi < 4; ++fi)
#pragma unroll
        for (int r = 0; r < 4; ++r) {
          int rowg = m0 + wr * 64 + fi * 16 + lg * 4 + r;
          int bbb = rowg / SEQ;
          int sr = rowg - bbb * SEQ;
          __hip_bfloat16 hv = __float2bfloat16(acc[fi][fj][r] + bias);
          if (which == 0)
            qbuf[(((size_t)(bbb * NH + hh)) * SEQ + sr) * HD + dd] = hv;
          else if (which == 1)
            kbuf[(((size_t)(bbb * NH + hh)) * SEQ + sr) * HD + dd] = hv;
          else
            vt[(((size_t)(bbb * NH + hh)) * HD + dd) * SEQ + sr] = hv;
        }
    }
  } else {
#pragma unroll
    for (int fj = 0; fj < 4; ++fj) {
      int ncol = n0 + wc * 64 + fj * 16 + lr;
      float bias = bo[ncol];
#pragma unroll
      for (int fi = 0; fi < 4; ++fi)
#pragma unroll
        for (int r = 0; r < 4; ++r) {
          int rowg = m0 + wr * 64 + fi * 16 + lg * 4 + r;
          outp[(size_t)rowg * DMODEL + ncol] = acc[fi][fj][r] + bias;
        }
    }
  }
}

// ---------- RMSNorm (full-D) + 3D-grid RoPE, in-place on q,k ----------
__global__ __launch_bounds__(256) void rmsrope_kernel(
    __hip_bfloat16* __restrict__ qb, __hip_bfloat16* __restrict__ kb,
    const float* __restrict__ gq, const float* __restrict__ gk,
    const float* __restrict__ fc, const float* __restrict__ fs,
    const int* __restrict__ gsz, const int* __restrict__ nmod)
{
  const int bs = blockIdx.x;
  const int b = bs / SEQ, s = bs - b * SEQ;
  const int t = threadIdx.x;
  const int f = gsz[0], h = gsz[1], wd = gsz[2];
  const int mm = nmod[0];
  const int seq_per = f * h * wd;
  int total_len = seq_per * mm; if (total_len > SEQ) total_len = SEQ;
  const bool dorope = s < total_len;
  int fi = 0, hi2 = 0, wi = 0;
  if (dorope) {
    int p = s % seq_per;
    fi = p / (h * wd);
    int rem = p - fi * (h * wd);
    hi2 = rem / wd;
    wi = rem - hi2 * wd;
  }
  float qv[3][2], kv[3][2];
  float sq = 0.f, sk = 0.f;
#pragma unroll
  for (int r = 0; r < 3; ++r) {
    int pi = t + r * 256;
    int head = pi >> 6;
    int dd = (pi & 63) * 2;
    size_t addr = (((size_t)(b * NH + head)) * SEQ + s) * HD + dd;
    __hip_bfloat162 q2 = *reinterpret_cast<const __hip_bfloat162*>(&qb[addr]);
    __hip_bfloat162 k2 = *reinterpret_cast<const __hip_bfloat162*>(&kb[addr]);
    qv[r][0] = __bfloat162float(q2.x); qv[r][1] = __bfloat162float(q2.y);
    kv[r][0] = __bfloat162float(k2.x); kv[r][1] = __bfloat162float(k2.y);
    sq += qv[r][0] * qv[r][0] + qv[r][1] * qv[r][1];
    sk += kv[r][0] * kv[r][0] + kv[r][1] * kv[r][1];
  }
#pragma unroll
  for (int off = 1; off < 64; off <<= 1) {
    sq += __shfl_xor(sq, off);
    sk += __shfl_xor(sk, off);
  }
  __shared__ float red[2][4];
  if ((t & 63) == 0) { red[0][t >> 6] = sq; red[1][t >> 6] = sk; }
  __syncthreads();
  float tq = red[0][0] + red[0][1] + red[0][2] + red[0][3];
  float tk = red[1][0] + red[1][1] + red[1][2] + red[1][3];
  float rq = rsqrtf(tq * (1.0f / DMODEL) + 1e-6f);
  float rk = rsqrtf(tk * (1.0f / DMODEL) + 1e-6f);
  const float scale = 0.08838834764831845f; // 1/sqrt(128), folded into q
#pragma unroll
  for (int r = 0; r < 3; ++r) {
    int pi = t + r * 256;
    int head = pi >> 6;
    int dd = (pi & 63) * 2;
    int col = pi * 2;
    size_t addr = (((size_t)(b * NH + head)) * SEQ + s) * HD + dd;
    float q0 = qv[r][0] * rq * gq[col], q1 = qv[r][1] * rq * gq[col + 1];
    float k0 = kv[r][0] * rk * gk[col], k1 = kv[r][1] * rk * gk[col + 1];
    if (dorope) {
      int j = pi & 63;
      int row = (j < 22) ? fi : (j < 43) ? hi2 : wi;
      float co = fc[row * 64 + j], si = fs[row * 64 + j];
      float a;
      a = q0 * co - q1 * si; q1 = q0 * si + q1 * co; q0 = a;
      a = k0 * co - k1 * si; k1 = k0 * si + k1 * co; k0 = a;
    }
    q0 *= scale; q1 *= scale;
    __hip_bfloat162 oq, ok;
    oq.x = __float2bfloat16(q0); oq.y = __float2bfloat16(q1);
    ok.x = __float2bfloat16(k0); ok.y = __float2bfloat16(k1);
    *reinterpret_cast<__hip_bfloat162*>(&qb[addr]) = oq;
    *reinterpret_cast<__hip_bfloat162*>(&kb[addr]) = ok;
  }
}

// ---------- flash attention v10: 4 waves x QBLK=32, K AND V LDS-staged ----------
// R9 post-mortem: all 4 waves loaded IDENTICAL V fragments from global (4x
// redundant, 64KB/tile/block) and the per-XCD K/V working set (5.4MB) exceeds
// the 4MB L2 -> L2/L3-BW-bound. Fix: stage V once per block into LDS (dbuf,
// XOR-swizzled 128B rows), halving per-tile traffic 96KB -> 48KB.
__global__ __launch_bounds__(256, 2) void attn_kernel(
    const __hip_bfloat16* __restrict__ qb, const __hip_bfloat16* __restrict__ kbuf,
    const __hip_bfloat16* __restrict__ vt, const int* __restrict__ seq_lens,
    __hip_bfloat16* __restrict__ ob)
{
  const int orig = blockIdx.x;
  const int wg = (orig & 7) * 84 + (orig >> 3);
  const int bh = wg / 14, qt = wg % 14;
  const int bbb = bh / NH, hh = bh - bbb * NH;
  const int tid = threadIdx.x;
  const int w = tid >> 6, l = tid & 63;
  const int lq = l & 31, h = l >> 5;
  const int sl = seq_lens[bbb];
  const __hip_bfloat16* Q = qb + (size_t)bh * SEQ * HD;
  const char* Kc = (const char*)(kbuf + (size_t)bh * SEQ * HD);
  const __hip_bfloat16* Vp = vt + (size_t)bh * HD * SEQ;   // [128][1792]
  const int q0 = qt * 128 + w * 32;

  __shared__ __hip_bfloat16 Kt[2][64 * 128];   // K tile, 256B rows, ^((row&7)<<4)
  __shared__ __hip_bfloat16 Vt[2][128 * 64];   // V^T tile [d][k], 128B rows, ^((row&7)<<4)

  bf16x8 qf[8];
#pragma unroll
  for (int kc = 0; kc < 8; ++kc)
    qf[kc] = *reinterpret_cast<const bf16x8*>(
        &Q[(size_t)(q0 + lq) * HD + kc * 16 + h * 8]);

  f32x16 oacc[4] = {};                          // O[q_off][d0*32+lq]
  float m = -3e38f, ll = 0.f;                   // per-lane q-row softmax state

  const int nkt = (sl + 63) >> 6;

  auto stageK = [&](int buf, int k0) {
    char* Lb = (char*)&Kt[buf][0];
#pragma unroll
    for (int q2 = 0; q2 < 4; ++q2) {
      int chunk = q2 * 256 + tid;               // 16B chunk id in [0,1024)
      int row = chunk >> 4;                     // 16 chunks per 256B row
      int cb = (chunk & 15) << 4;
      int scb = cb ^ ((row & 7) << 4);          // inverse-swizzled source
      gload16(Kc + (size_t)(k0 + row) * 256 + scb, Lb + chunk * 16);
    }
  };
  auto stageV = [&](int buf, int k0) {
    char* Lb = (char*)&Vt[buf][0];
#pragma unroll
    for (int q2 = 0; q2 < 4; ++q2) {
      int chunk = q2 * 256 + tid;               // 16B chunk id in [0,1024)
      int row = chunk >> 3;                     // 8 chunks per 128B row; row = d in [0,128)
      int cb = (chunk & 7) << 4;
      int scb = cb ^ ((row & 7) << 4);          // inverse-swizzled source (bytes)
      gload16(Vp + (size_t)row * SEQ + k0 + (scb >> 1), Lb + chunk * 16);
    }
  };

  stageK(0, 0);
  stageV(0, 0);
  for (int kt = 0; kt < nkt; ++kt) {
    __syncthreads();                            // stage(kt) drained; prev compute done
    const int k0 = kt * 64;
    if (kt + 1 < nkt) { stageK((kt + 1) & 1, k0 + 64); stageV((kt + 1) & 1, k0 + 64); }
    const char* Kl = (const char*)&Kt[kt & 1][0];
    const char* Vl = (const char*)&Vt[kt & 1][0];

    // swapped QK^T: S^T[k][q], 16 ds_read_b128 + 16 mfma_32x32x16
    f32x16 sa[2] = {};
#pragma unroll
    for (int cb = 0; cb < 2; ++cb) {
      int row = cb * 32 + lq;
      int swz = (row & 7) << 4;
#pragma unroll
      for (int kc = 0; kc < 8; ++kc) {
        bf16x8 kf = *reinterpret_cast<const bf16x8*>(
            Kl + row * 256 + ((kc * 32 + h * 16) ^ swz));
        sa[cb] = __builtin_amdgcn_mfma_f32_32x32x16_bf16(kf, qf[kc], sa[cb], 0, 0, 0);
      }
    }

    // mask tail (rare): k of sa[cb][r] = k0 + cb*32 + (r&3) + 8*(r>>2) + 4*h
    if (k0 + 64 > sl) {
#pragma unroll
      for (int cb = 0; cb < 2; ++cb)
#pragma unroll
        for (int r = 0; r < 16; ++r) {
          int kg = k0 + cb * 32 + (r & 3) + 8 * (r >> 2) + 4 * h;
          if (kg >= sl) sa[cb][r] = -3e38f;
        }
    }

    // in-register online softmax: lane owns q-row (lq), halves split across h
    float mx = -3e38f;
#pragma unroll
    for (int cb = 0; cb < 2; ++cb)
#pragma unroll
      for (int r = 0; r < 16; ++r) mx = fmaxf(mx, sa[cb][r]);
    mx = fmaxf(mx, __shfl_xor(mx, 32));

    if (__any(mx - m > 8.f)) {                  // defer-max (T13)
      float mn = fmaxf(m, mx);
      float alpha = __expf(m - mn);
      m = mn;
      ll *= alpha;
#pragma unroll
      for (int r = 0; r < 16; ++r) {
        float ar = __shfl(alpha, (r & 3) + 8 * (r >> 2) + 4 * h);
#pragma unroll
        for (int d0 = 0; d0 < 4; ++d0) oacc[d0][r] *= ar;
      }
    }

    float rs = 0.f;
#pragma unroll
    for (int cb = 0; cb < 2; ++cb)
#pragma unroll
      for (int r = 0; r < 16; ++r) {
        float e = __expf(sa[cb][r] - m);
        sa[cb][r] = e;
        rs += e;
      }
    rs += __shfl_xor(rs, 32);
    ll += rs;

    // P -> bf16 A-frags (pack + shfl_xor(32) exchange) and PV (V from LDS)
#pragma unroll
    for (int c = 0; c < 4; ++c) {
      const int cb = c >> 1, r0 = 8 * (c & 1);
      unsigned A01 = pack2(sa[cb][r0],     sa[cb][r0 + 1]);
      unsigned A23 = pack2(sa[cb][r0 + 2], sa[cb][r0 + 3]);
      unsigned B01 = pack2(sa[cb][r0 + 4], sa[cb][r0 + 5]);
      unsigned B23 = pack2(sa[cb][r0 + 6], sa[cb][r0 + 7]);
      unsigned s1 = __shfl_xor(h ? A01 : B01, 32);
      unsigned s2 = __shfl_xor(h ? A23 : B23, 32);
      int4 wv;
      wv.x = (int)(h ? s1 : A01);
      wv.y = (int)(h ? s2 : A23);
      wv.z = (int)(h ? B01 : s1);
      wv.w = (int)(h ? B23 : s2);
      bf16x8 pa = *reinterpret_cast<bf16x8*>(&wv);
#pragma unroll
      for (int d0 = 0; d0 < 4; ++d0) {
        int vr = d0 * 32 + lq;
        bf16x8 vv = *reinterpret_cast<const bf16x8*>(
            Vl + vr * 128 + ((c * 32 + h * 16) ^ ((vr & 7) << 4)));
        oacc[d0] = __builtin_amdgcn_mfma_f32_32x32x16_bf16(pa, vv, oacc[d0], 0, 0, 0);
      }
    }
  }

  // epilogue: normalize by per-q-row sum, write O
  float invl = 1.0f / ll;
#pragma unroll
  for (int r = 0; r < 16; ++r) {
    int qoff = (r & 3) + 8 * (r >> 2) + 4 * h;
    float ir = __shfl(invl, qoff);
    int qrow = q0 + qoff;
#pragma unroll
    for (int d0 = 0; d0 < 4; ++d0)
      ob[((size_t)bbb * SEQ + qrow) * DMODEL + hh * HD + d0 * 32 + lq] =
          __float2bfloat16(oacc[d0][r] * ir);
  }
}

// ---------- launch ----------
extern "C" void kernel_launch(void* const* d_in, const int* in_sizes, int n_in,
                              void* d_out, int out_size, void* d_ws, size_t ws_size,
                              hipStream_t stream) {
  const float* x   = (const float*)d_in[0];
  const int* seq_lens   = (const int*)d_in[1];
  const int* grid_sizes = (const int*)d_in[2];
  const float* fc  = (const float*)d_in[3];
  const float* fs  = (const float*)d_in[4];
  const float* Wq  = (const float*)d_in[5];
  const float* bq  = (const float*)d_in[6];
  const float* Wk  = (const float*)d_in[7];
  const float* bk  = (const float*)d_in[8];
  const float* Wv  = (const float*)d_in[9];
  const float* bv  = (const float*)d_in[10];
  const float* Wo  = (const float*)d_in[11];
  const float* bo  = (const float*)d_in[12];
  const float* gq  = (const float*)d_in[13];
  const float* gk  = (const float*)d_in[14];
  const int* nmod  = (const int*)d_in[15];
  float* out = (float*)d_out;

  char* ws = (char*)d_ws;
  __hip_bfloat16* xb   = (__hip_bfloat16*)(ws + 0);           // [7168][1536]
  __hip_bfloat16* wb   = (__hip_bfloat16*)(ws + 22020096);    // [4608][1536]
  __hip_bfloat16* wob  = (__hip_bfloat16*)(ws + 36175872);    // [1536][1536]
  __hip_bfloat16* qbuf = (__hip_bfloat16*)(ws + 40894464);    // [48][1792][128]
  __hip_bfloat16* kbuf = (__hip_bfloat16*)(ws + 62914560);    // [48][1792][128]
  __hip_bfloat16* vtb  = (__hip_bfloat16*)(ws + 84934656);    // [48][128][1792]
  __hip_bfloat16* ob   = xb;                                  // O reuses xb region

  cast_all_kernel<<<(5111808 + 255) / 256, 256, 0, stream>>>(x, Wq, Wk, Wv, Wo, xb, wb, wob);

  gemm_bt<0><<<dim3(36, 56), 256, 0, stream>>>(xb, wb, 1536, bq, bk, bv,
                                               qbuf, kbuf, vtb, nullptr, nullptr);
  rmsrope_kernel<<<7168, 256, 0, stream>>>(qbuf, kbuf, gq, gk, fc, fs, grid_sizes, nmod);
  attn_kernel<<<672, 256, 0, stream>>>(qbuf, kbuf, vtb, seq_lens, ob);
  gemm_bt<1><<<dim3(12, 56), 256, 0, stream>>>(ob, wob, 1536, nullptr, nullptr, nullptr,
                                               nullptr, nullptr, nullptr, bo, out);
}

// Round 11
// 341.998 us; speedup vs baseline: 1.3983x; 1.1405x over previous
//
#include <hip/hip_runtime.h>
#include <hip/hip_bf16.h>

typedef short bf16x8 __attribute__((ext_vector_type(8)));
typedef float f32x4 __attribute__((ext_vector_type(4)));
typedef float f32x16 __attribute__((ext_vector_type(16)));

#define NH 12
#define SEQ 1792
#define DMODEL 1536
#define HD 128

static __device__ __forceinline__ void gload16(const void* g, void* l) {
  __builtin_amdgcn_global_load_lds((const __attribute__((address_space(1))) void*)g,
                                   (__attribute__((address_space(3))) void*)l, 16, 0, 0);
}

static __device__ __forceinline__ short f2bf(float x) {
  __hip_bfloat16 h = __float2bfloat16(x);
  return *reinterpret_cast<short*>(&h);
}

static __device__ __forceinline__ unsigned pack2(float lo, float hi) {
  unsigned a = (unsigned)(unsigned short)f2bf(lo);
  unsigned b = (unsigned)(unsigned short)f2bf(hi);
  return a | (b << 16);
}

// ---------- fused fp32 -> bf16 cast for x + Wq + Wk + Wv + Wo (one launch) ----------
__global__ __launch_bounds__(256) void cast_all_kernel(
    const float* __restrict__ x, const float* __restrict__ wq, const float* __restrict__ wk,
    const float* __restrict__ wv, const float* __restrict__ wo,
    __hip_bfloat16* __restrict__ xb, __hip_bfloat16* __restrict__ wb,
    __hip_bfloat16* __restrict__ wob) {
  int i = blockIdx.x * 256 + threadIdx.x;
  const float* src; __hip_bfloat16* dst; int j;
  if (i < 2752512)      { src = x;  dst = xb;            j = i; }
  else if (i < 3342336) { src = wq; dst = wb;            j = i - 2752512; }
  else if (i < 3932160) { src = wk; dst = wb + 2359296;  j = i - 3342336; }
  else if (i < 4521984) { src = wv; dst = wb + 4718592;  j = i - 3932160; }
  else if (i < 5111808) { src = wo; dst = wob;           j = i - 4521984; }
  else return;
  float4 v = reinterpret_cast<const float4*>(src)[j];
  short4 r;
  r.x = f2bf(v.x); r.y = f2bf(v.y); r.z = f2bf(v.z); r.w = f2bf(v.w);
  reinterpret_cast<short4*>(dst)[j] = r;
}

// ---------- 256x256 bf16 GEMM, 8-phase schedule (T2+T3+T4+T5), C = A @ B^T ----------
// BM=BN=256, BK=64, 8 waves (2M x 4N), 512 thr. LDS 128 KB: As/Bs[par][half][128*64],
// XOR-swizzled (byte ^= (row&7)<<4; linear gload_lds dest + inverse-swizzled src).
// 8 phases per iteration = 2 K-tiles; 1 half-tile staged per phase; counted vmcnt(2)
// at end-P3/end-P7 only (drains exactly the next tile's 4 halves); lgkmcnt(0)+
// sched_barrier before each 16-MFMA setprio cluster.
// MODE 0: QKV epilogue (bias + scatter q/k per-head row-major, v transposed)
// MODE 1: fp32 epilogue (bias)
template<int MODE>
__global__ __launch_bounds__(512, 2) void gemm8(
    const __hip_bfloat16* __restrict__ A, const __hip_bfloat16* __restrict__ B,
    int nN, int cpx,
    const float* __restrict__ bq, const float* __restrict__ bk, const float* __restrict__ bv,
    __hip_bfloat16* __restrict__ qbuf, __hip_bfloat16* __restrict__ kbuf,
    __hip_bfloat16* __restrict__ vt,
    const float* __restrict__ bo, float* __restrict__ outp)
{
  constexpr int K = DMODEL;                  // 1536
  constexpr int nT = K / 64;                 // 24 K-tiles
  constexpr int nIt = nT / 2;                // 12 iterations
  __shared__ __hip_bfloat16 As[2][2][128 * 64];   // [parity][half] 64 KB
  __shared__ __hip_bfloat16 Bs[2][2][128 * 64];   // 64 KB
  const int tid = threadIdx.x;
  const int l = tid & 63, w = tid >> 6;
  const int lr = l & 15, lg = l >> 4;
  const int wr = w >> 2, wc = w & 3;         // 2 x 4 wave grid

  const int orig = blockIdx.x;               // bijective XCD swizzle (grid = 8*cpx)
  const int wg = (orig & 7) * cpx + (orig >> 3);
  const int m0 = (wg / nN) * 256, n0 = (wg % nN) * 256;

  // staging thread-constants: 1024 chunks/half-tile, thread -> chunks {tid, tid+512}
  const int hrow0 = tid >> 3;                 // row of first chunk (0..63)
  const int scb0 = ((tid & 7) << 4) ^ ((hrow0 & 7) << 4);  // inverse-swizzled src col

  auto stageA = [&](int t, int half) {
    const char* s = (const char*)(A + (size_t)(m0 + half * 128) * K + t * 64);
    char* d = (char*)&As[t & 1][half][0];
    gload16(s + (size_t)hrow0 * (K * 2) + scb0, d + tid * 16);
    gload16(s + (size_t)(hrow0 + 64) * (K * 2) + scb0, d + (tid + 512) * 16);
  };
  auto stageB = [&](int t, int half) {
    const char* s = (const char*)(B + (size_t)(n0 + half * 128) * K + t * 64);
    char* d = (char*)&Bs[t & 1][half][0];
    gload16(s + (size_t)hrow0 * (K * 2) + scb0, d + tid * 16);
    gload16(s + (size_t)(hrow0 + 64) * (K * 2) + scb0, d + (tid + 512) * 16);
  };

  f32x4 acc[8][4] = {};
  bf16x8 afr[4][2], b0f[2][2], b1f[2][2];

  auto rdA = [&](int par, int mh) {
#pragma unroll
    for (int i = 0; i < 4; ++i) {
      int hrow = (mh * 4 + i) * 16 + lr;     // row within the wave's 128-row (=wr) half
#pragma unroll
      for (int ks = 0; ks < 2; ++ks)
        afr[i][ks] = *reinterpret_cast<const bf16x8*>(
            (const char*)&As[par][wr][0] + hrow * 128 +
            ((ks * 64 + lg * 16) ^ ((hrow & 7) << 4)));
    }
  };
  auto rdB = [&](int par, int nh, bf16x8 (&bqf)[2][2]) {
#pragma unroll
    for (int j = 0; j < 2; ++j) {
      int base = wc * 64 + (nh * 2 + j) * 16;  // multiple of 16; half uniform per (wc,fj)
      int half = base >> 7;
      int hrow = (base & 127) + lr;
#pragma unroll
      for (int ks = 0; ks < 2; ++ks)
        bqf[j][ks] = *reinterpret_cast<const bf16x8*>(
            (const char*)&Bs[par][half][0] + hrow * 128 +
            ((ks * 64 + lg * 16) ^ ((hrow & 7) << 4)));
    }
  };
  auto mf = [&](int mh, int nh, bf16x8 (&bqf)[2][2]) {
    __builtin_amdgcn_s_setprio(1);
#pragma unroll
    for (int i = 0; i < 4; ++i)
#pragma unroll
      for (int j = 0; j < 2; ++j)
#pragma unroll
        for (int ks = 0; ks < 2; ++ks)
          acc[mh * 4 + i][nh * 2 + j] = __builtin_amdgcn_mfma_f32_16x16x32_bf16(
              afr[i][ks], bqf[j][ks], acc[mh * 4 + i][nh * 2 + j], 0, 0, 0);
    __builtin_amdgcn_s_setprio(0);
  };

#define LGKM0 do { asm volatile("s_waitcnt lgkmcnt(0)" ::: "memory"); \
                   __builtin_amdgcn_sched_barrier(0); } while (0)
#define BAR __builtin_amdgcn_s_barrier()

  // prologue = virtual P3..P7 of iteration -1: tile0 fully + A[1,h0]
  stageA(0, 0); stageA(0, 1); stageB(0, 0); stageB(0, 1); stageA(1, 0);
  asm volatile("s_waitcnt vmcnt(2)" ::: "memory");   // tile0's 4 halves landed (all waves ditto pre-barrier)
  BAR;

  for (int it = 0; it < nIt; ++it) {
    const int t1 = 2 * it + 1, u0 = 2 * it + 2, u1 = 2 * it + 3;
    // ===== K-tile t0 = 2it (parity 0) =====
    // P0: quadrant (mh0, nh0)
    rdA(0, 0); rdB(0, 0, b0f);                 // 12 ds_read_b128
    stageA(t1, 1);
    LGKM0; mf(0, 0, b0f); BAR;
    // P1: (mh0, nh1)
    rdB(0, 1, b1f);                            // 4
    stageB(t1, 0);
    LGKM0; mf(0, 1, b1f); BAR;
    // P2: (mh1, nh1)
    rdA(0, 1);                                 // 8
    stageB(t1, 1);
    LGKM0; mf(1, 1, b1f); BAR;
    // P3: (mh1, nh0) — register-only
    if (u0 < nT) stageA(u0, 0);
    mf(1, 0, b0f);
    if (it + 1 == nIt) asm volatile("s_waitcnt vmcnt(0)" ::: "memory");
    else               asm volatile("s_waitcnt vmcnt(2)" ::: "memory");  // t1's 4 halves landed
    BAR;
    // ===== K-tile t1 = 2it+1 (parity 1) =====
    // P4
    rdA(1, 0); rdB(1, 0, b0f);
    if (u0 < nT) stageA(u0, 1);
    LGKM0; mf(0, 0, b0f); BAR;
    // P5
    rdB(1, 1, b1f);
    if (u0 < nT) stageB(u0, 0);
    LGKM0; mf(0, 1, b1f); BAR;
    // P6
    rdA(1, 1);
    if (u0 < nT) stageB(u0, 1);
    LGKM0; mf(1, 1, b1f); BAR;
    // P7
    if (u1 < nT) stageA(u1, 0);
    mf(1, 0, b0f);
    asm volatile("s_waitcnt vmcnt(2)" ::: "memory");   // u0's 4 halves landed
    BAR;
  }
#undef LGKM0
#undef BAR

  // ---- epilogue ----
  if (MODE == 0) {
#pragma unroll
    for (int fj = 0; fj < 4; ++fj) {
      int ncol = n0 + wc * 64 + fj * 16 + lr;   // 0..4607
      int which = ncol / DMODEL;                // uniform per block (n-tile within segment)
      int cc = ncol - which * DMODEL;
      int hh = cc >> 7, dd = cc & 127;
      float bias = (which == 0 ? bq : which == 1 ? bk : bv)[cc];
#pragma unroll
      for (int fi = 0; fi < 8; ++fi)
#pragma unroll
        for (int r = 0; r < 4; ++r) {
          int rowg = m0 + wr * 128 + fi * 16 + lg * 4 + r;
          int bbb = rowg / SEQ;
          int sr = rowg - bbb * SEQ;
          __hip_bfloat16 hv = __float2bfloat16(acc[fi][fj][r] + bias);
          if (which == 0)
            qbuf[(((size_t)(bbb * NH + hh)) * SEQ + sr) * HD + dd] = hv;
          else if (which == 1)
            kbuf[(((size_t)(bbb * NH + hh)) * SEQ + sr) * HD + dd] = hv;
          else
            vt[(((size_t)(bbb * NH + hh)) * HD + dd) * SEQ + sr] = hv;
        }
    }
  } else {
#pragma unroll
    for (int fj = 0; fj < 4; ++fj) {
      int ncol = n0 + wc * 64 + fj * 16 + lr;
      float bias = bo[ncol];
#pragma unroll
      for (int fi = 0; fi < 8; ++fi)
#pragma unroll
        for (int r = 0; r < 4; ++r) {
          int rowg = m0 + wr * 128 + fi * 16 + lg * 4 + r;
          outp[(size_t)rowg * DMODEL + ncol] = acc[fi][fj][r] + bias;
        }
    }
  }
}

// ---------- RMSNorm (full-D) + 3D-grid RoPE, in-place on q,k ----------
__global__ __launch_bounds__(256) void rmsrope_kernel(
    __hip_bfloat16* __restrict__ qb, __hip_bfloat16* __restrict__ kb,
    const float* __restrict__ gq, const float* __restrict__ gk,
    const float* __restrict__ fc, const float* __restrict__ fs,
    const int* __restrict__ gsz, const int* __restrict__ nmod)
{
  const int bs = blockIdx.x;
  const int b = bs / SEQ, s = bs - b * SEQ;
  const int t = threadIdx.x;
  const int f = gsz[0], h = gsz[1], wd = gsz[2];
  const int mm = nmod[0];
  const int seq_per = f * h * wd;
  int total_len = seq_per * mm; if (total_len > SEQ) total_len = SEQ;
  const bool dorope = s < total_len;
  int fi = 0, hi2 = 0, wi = 0;
  if (dorope) {
    int p = s % seq_per;
    fi = p / (h * wd);
    int rem = p - fi * (h * wd);
    hi2 = rem / wd;
    wi = rem - hi2 * wd;
  }
  float qv[3][2], kv[3][2];
  float sq = 0.f, sk = 0.f;
#pragma unroll
  for (int r = 0; r < 3; ++r) {
    int pi = t + r * 256;
    int head = pi >> 6;
    int dd = (pi & 63) * 2;
    size_t addr = (((size_t)(b * NH + head)) * SEQ + s) * HD + dd;
    __hip_bfloat162 q2 = *reinterpret_cast<const __hip_bfloat162*>(&qb[addr]);
    __hip_bfloat162 k2 = *reinterpret_cast<const __hip_bfloat162*>(&kb[addr]);
    qv[r][0] = __bfloat162float(q2.x); qv[r][1] = __bfloat162float(q2.y);
    kv[r][0] = __bfloat162float(k2.x); kv[r][1] = __bfloat162float(k2.y);
    sq += qv[r][0] * qv[r][0] + qv[r][1] * qv[r][1];
    sk += kv[r][0] * kv[r][0] + kv[r][1] * kv[r][1];
  }
#pragma unroll
  for (int off = 1; off < 64; off <<= 1) {
    sq += __shfl_xor(sq, off);
    sk += __shfl_xor(sk, off);
  }
  __shared__ float red[2][4];
  if ((t & 63) == 0) { red[0][t >> 6] = sq; red[1][t >> 6] = sk; }
  __syncthreads();
  float tq = red[0][0] + red[0][1] + red[0][2] + red[0][3];
  float tk = red[1][0] + red[1][1] + red[1][2] + red[1][3];
  float rq = rsqrtf(tq * (1.0f / DMODEL) + 1e-6f);
  float rk = rsqrtf(tk * (1.0f / DMODEL) + 1e-6f);
  const float scale = 0.08838834764831845f; // 1/sqrt(128), folded into q
#pragma unroll
  for (int r = 0; r < 3; ++r) {
    int pi = t + r * 256;
    int head = pi >> 6;
    int dd = (pi & 63) * 2;
    int col = pi * 2;
    size_t addr = (((size_t)(b * NH + head)) * SEQ + s) * HD + dd;
    float q0 = qv[r][0] * rq * gq[col], q1 = qv[r][1] * rq * gq[col + 1];
    float k0 = kv[r][0] * rk * gk[col], k1 = kv[r][1] * rk * gk[col + 1];
    if (dorope) {
      int j = pi & 63;
      int row = (j < 22) ? fi : (j < 43) ? hi2 : wi;
      float co = fc[row * 64 + j], si = fs[row * 64 + j];
      float a;
      a = q0 * co - q1 * si; q1 = q0 * si + q1 * co; q0 = a;
      a = k0 * co - k1 * si; k1 = k0 * si + k1 * co; k0 = a;
    }
    q0 *= scale; q1 *= scale;
    __hip_bfloat162 oq, ok;
    oq.x = __float2bfloat16(q0); oq.y = __float2bfloat16(q1);
    ok.x = __float2bfloat16(k0); ok.y = __float2bfloat16(k1);
    *reinterpret_cast<__hip_bfloat162*>(&qb[addr]) = oq;
    *reinterpret_cast<__hip_bfloat162*>(&kb[addr]) = ok;
  }
}

// ---------- flash attention v10: 4 waves x QBLK=32, K AND V LDS-staged ----------
__global__ __launch_bounds__(256, 2) void attn_kernel(
    const __hip_bfloat16* __restrict__ qb, const __hip_bfloat16* __restrict__ kbuf,
    const __hip_bfloat16* __restrict__ vt, const int* __restrict__ seq_lens,
    __hip_bfloat16* __restrict__ ob)
{
  const int orig = blockIdx.x;
  const int wg = (orig & 7) * 84 + (orig >> 3);
  const int bh = wg / 14, qt = wg % 14;
  const int bbb = bh / NH, hh = bh - bbb * NH;
  const int tid = threadIdx.x;
  const int w = tid >> 6, l = tid & 63;
  const int lq = l & 31, h = l >> 5;
  const int sl = seq_lens[bbb];
  const __hip_bfloat16* Q = qb + (size_t)bh * SEQ * HD;
  const char* Kc = (const char*)(kbuf + (size_t)bh * SEQ * HD);
  const __hip_bfloat16* Vp = vt + (size_t)bh * HD * SEQ;   // [128][1792]
  const int q0 = qt * 128 + w * 32;

  __shared__ __hip_bfloat16 Kt[2][64 * 128];   // K tile, 256B rows, ^((row&7)<<4)
  __shared__ __hip_bfloat16 Vt[2][128 * 64];   // V^T tile [d][k], 128B rows, ^((row&7)<<4)

  bf16x8 qf[8];
#pragma unroll
  for (int kc = 0; kc < 8; ++kc)
    qf[kc] = *reinterpret_cast<const bf16x8*>(
        &Q[(size_t)(q0 + lq) * HD + kc * 16 + h * 8]);

  f32x16 oacc[4] = {};                          // O[q_off][d0*32+lq]
  float m = -3e38f, ll = 0.f;                   // per-lane q-row softmax state

  const int nkt = (sl + 63) >> 6;

  auto stageK = [&](int buf, int k0) {
    char* Lb = (char*)&Kt[buf][0];
#pragma unroll
    for (int q2 = 0; q2 < 4; ++q2) {
      int chunk = q2 * 256 + tid;
      int row = chunk >> 4;
      int cb = (chunk & 15) << 4;
      int scb = cb ^ ((row & 7) << 4);
      gload16(Kc + (size_t)(k0 + row) * 256 + scb, Lb + chunk * 16);
    }
  };
  auto stageV = [&](int buf, int k0) {
    char* Lb = (char*)&Vt[buf][0];
#pragma unroll
    for (int q2 = 0; q2 < 4; ++q2) {
      int chunk = q2 * 256 + tid;
      int row = chunk >> 3;
      int cb = (chunk & 7) << 4;
      int scb = cb ^ ((row & 7) << 4);
      gload16(Vp + (size_t)row * SEQ + k0 + (scb >> 1), Lb + chunk * 16);
    }
  };

  stageK(0, 0);
  stageV(0, 0);
  for (int kt = 0; kt < nkt; ++kt) {
    __syncthreads();
    const int k0 = kt * 64;
    if (kt + 1 < nkt) { stageK((kt + 1) & 1, k0 + 64); stageV((kt + 1) & 1, k0 + 64); }
    const char* Kl = (const char*)&Kt[kt & 1][0];
    const char* Vl = (const char*)&Vt[kt & 1][0];

    f32x16 sa[2] = {};
#pragma unroll
    for (int cb = 0; cb < 2; ++cb) {
      int row = cb * 32 + lq;
      int swz = (row & 7) << 4;
#pragma unroll
      for (int kc = 0; kc < 8; ++kc) {
        bf16x8 kf = *reinterpret_cast<const bf16x8*>(
            Kl + row * 256 + ((kc * 32 + h * 16) ^ swz));
        sa[cb] = __builtin_amdgcn_mfma_f32_32x32x16_bf16(kf, qf[kc], sa[cb], 0, 0, 0);
      }
    }

    if (k0 + 64 > sl) {
#pragma unroll
      for (int cb = 0; cb < 2; ++cb)
#pragma unroll
        for (int r = 0; r < 16; ++r) {
          int kg = k0 + cb * 32 + (r & 3) + 8 * (r >> 2) + 4 * h;
          if (kg >= sl) sa[cb][r] = -3e38f;
        }
    }

    float mx = -3e38f;
#pragma unroll
    for (int cb = 0; cb < 2; ++cb)
#pragma unroll
      for (int r = 0; r < 16; ++r) mx = fmaxf(mx, sa[cb][r]);
    mx = fmaxf(mx, __shfl_xor(mx, 32));

    if (__any(mx - m > 8.f)) {                  // defer-max (T13)
      float mn = fmaxf(m, mx);
      float alpha = __expf(m - mn);
      m = mn;
      ll *= alpha;
#pragma unroll
      for (int r = 0; r < 16; ++r) {
        float ar = __shfl(alpha, (r & 3) + 8 * (r >> 2) + 4 * h);
#pragma unroll
        for (int d0 = 0; d0 < 4; ++d0) oacc[d0][r] *= ar;
      }
    }

    float rs = 0.f;
#pragma unroll
    for (int cb = 0; cb < 2; ++cb)
#pragma unroll
      for (int r = 0; r < 16; ++r) {
        float e = __expf(sa[cb][r] - m);
        sa[cb][r] = e;
        rs += e;
      }
    rs += __shfl_xor(rs, 32);
    ll += rs;

#pragma unroll
    for (int c = 0; c < 4; ++c) {
      const int cb = c >> 1, r0 = 8 * (c & 1);
      unsigned A01 = pack2(sa[cb][r0],     sa[cb][r0 + 1]);
      unsigned A23 = pack2(sa[cb][r0 + 2], sa[cb][r0 + 3]);
      unsigned B01 = pack2(sa[cb][r0 + 4], sa[cb][r0 + 5]);
      unsigned B23 = pack2(sa[cb][r0 + 6], sa[cb][r0 + 7]);
      unsigned s1 = __shfl_xor(h ? A01 : B01, 32);
      unsigned s2 = __shfl_xor(h ? A23 : B23, 32);
      int4 wv;
      wv.x = (int)(h ? s1 : A01);
      wv.y = (int)(h ? s2 : A23);
      wv.z = (int)(h ? B01 : s1);
      wv.w = (int)(h ? B23 : s2);
      bf16x8 pa = *reinterpret_cast<bf16x8*>(&wv);
#pragma unroll
      for (int d0 = 0; d0 < 4; ++d0) {
        int vr = d0 * 32 + lq;
        bf16x8 vv = *reinterpret_cast<const bf16x8*>(
            Vl + vr * 128 + ((c * 32 + h * 16) ^ ((vr & 7) << 4)));
        oacc[d0] = __builtin_amdgcn_mfma_f32_32x32x16_bf16(pa, vv, oacc[d0], 0, 0, 0);
      }
    }
  }

  float invl = 1.0f / ll;
#pragma unroll
  for (int r = 0; r < 16; ++r) {
    int qoff = (r & 3) + 8 * (r >> 2) + 4 * h;
    float ir = __shfl(invl, qoff);
    int qrow = q0 + qoff;
#pragma unroll
    for (int d0 = 0; d0 < 4; ++d0)
      ob[((size_t)bbb * SEQ + qrow) * DMODEL + hh * HD + d0 * 32 + lq] =
          __float2bfloat16(oacc[d0][r] * ir);
  }
}

// ---------- launch ----------
extern "C" void kernel_launch(void* const* d_in, const int* in_sizes, int n_in,
                              void* d_out, int out_size, void* d_ws, size_t ws_size,
                              hipStream_t stream) {
  const float* x   = (const float*)d_in[0];
  const int* seq_lens   = (const int*)d_in[1];
  const int* grid_sizes = (const int*)d_in[2];
  const float* fc  = (const float*)d_in[3];
  const float* fs  = (const float*)d_in[4];
  const float* Wq  = (const float*)d_in[5];
  const float* bq  = (const float*)d_in[6];
  const float* Wk  = (const float*)d_in[7];
  const float* bk  = (const float*)d_in[8];
  const float* Wv  = (const float*)d_in[9];
  const float* bv  = (const float*)d_in[10];
  const float* Wo  = (const float*)d_in[11];
  const float* bo  = (const float*)d_in[12];
  const float* gq  = (const float*)d_in[13];
  const float* gk  = (const float*)d_in[14];
  const int* nmod  = (const int*)d_in[15];
  float* out = (float*)d_out;

  char* ws = (char*)d_ws;
  __hip_bfloat16* xb   = (__hip_bfloat16*)(ws + 0);           // [7168][1536]
  __hip_bfloat16* wb   = (__hip_bfloat16*)(ws + 22020096);    // [4608][1536]
  __hip_bfloat16* wob  = (__hip_bfloat16*)(ws + 36175872);    // [1536][1536]
  __hip_bfloat16* qbuf = (__hip_bfloat16*)(ws + 40894464);    // [48][1792][128]
  __hip_bfloat16* kbuf = (__hip_bfloat16*)(ws + 62914560);    // [48][1792][128]
  __hip_bfloat16* vtb  = (__hip_bfloat16*)(ws + 84934656);    // [48][128][1792]
  __hip_bfloat16* ob   = xb;                                  // O reuses xb region

  cast_all_kernel<<<(5111808 + 255) / 256, 256, 0, stream>>>(x, Wq, Wk, Wv, Wo, xb, wb, wob);

  // QKV: M=7168 (28 tiles) x N=4608 (18 tiles) -> 504 = 8*63
  gemm8<0><<<504, 512, 0, stream>>>(xb, wb, 18, 63, bq, bk, bv,
                                    qbuf, kbuf, vtb, nullptr, nullptr);
  rmsrope_kernel<<<7168, 256, 0, stream>>>(qbuf, kbuf, gq, gk, fc, fs, grid_sizes, nmod);
  attn_kernel<<<672, 256, 0, stream>>>(qbuf, kbuf, vtb, seq_lens, ob);
  // out-proj: M=7168 (28) x N=1536 (6 tiles) -> 168 = 8*21
  gemm8<1><<<168, 512, 0, stream>>>(ob, wob, 6, 21, nullptr, nullptr, nullptr,
                                    nullptr, nullptr, nullptr, bo, out);
}

// Round 12
// 326.752 us; speedup vs baseline: 1.4635x; 1.0467x over previous
//
#include <hip/hip_runtime.h>
#include <hip/hip_bf16.h>

typedef short bf16x8 __attribute__((ext_vector_type(8)));
typedef float f32x4 __attribute__((ext_vector_type(4)));
typedef float f32x16 __attribute__((ext_vector_type(16)));

#define NH 12
#define SEQ 1792
#define DMODEL 1536
#define HD 128

static __device__ __forceinline__ void gload16(const void* g, void* l) {
  __builtin_amdgcn_global_load_lds((const __attribute__((address_space(1))) void*)g,
                                   (__attribute__((address_space(3))) void*)l, 16, 0, 0);
}

static __device__ __forceinline__ short f2bf(float x) {
  __hip_bfloat16 h = __float2bfloat16(x);
  return *reinterpret_cast<short*>(&h);
}

static __device__ __forceinline__ unsigned pack2(float lo, float hi) {
  unsigned a = (unsigned)(unsigned short)f2bf(lo);
  unsigned b = (unsigned)(unsigned short)f2bf(hi);
  return a | (b << 16);
}

// ---------- fused fp32 -> bf16 cast for x + Wq + Wk + Wv + Wo (one launch) ----------
__global__ __launch_bounds__(256) void cast_all_kernel(
    const float* __restrict__ x, const float* __restrict__ wq, const float* __restrict__ wk,
    const float* __restrict__ wv, const float* __restrict__ wo,
    __hip_bfloat16* __restrict__ xb, __hip_bfloat16* __restrict__ wb,
    __hip_bfloat16* __restrict__ wob) {
  int i = blockIdx.x * 256 + threadIdx.x;
  const float* src; __hip_bfloat16* dst; int j;
  if (i < 2752512)      { src = x;  dst = xb;            j = i; }
  else if (i < 3342336) { src = wq; dst = wb;            j = i - 2752512; }
  else if (i < 3932160) { src = wk; dst = wb + 2359296;  j = i - 3342336; }
  else if (i < 4521984) { src = wv; dst = wb + 4718592;  j = i - 3932160; }
  else if (i < 5111808) { src = wo; dst = wob;           j = i - 4521984; }
  else return;
  float4 v = reinterpret_cast<const float4*>(src)[j];
  short4 r;
  r.x = f2bf(v.x); r.y = f2bf(v.y); r.z = f2bf(v.z); r.w = f2bf(v.w);
  reinterpret_cast<short4*>(dst)[j] = r;
}

// ---------- 256x256 bf16 GEMM, 8-phase, reads pipelined ONE PHASE AHEAD ----------
// BM=BN=256, BK=64, 8 waves (2M x 4N). LDS 128 KB carved from LDSRAW:
// As[p][half] at p*32768+half*16384, Bs at +65536. XOR swizzle byte^=(row&7)<<4.
// Per tile t (4 phases), quadrant Q_i's ds_reads issue in phase i-1 so their
// ~120cy latency spans a barrier. vmcnt(2) at end-P2 (tile t+1 landed), so P3's
// next-tile reads are safe. MODE 0 v-blocks: epilogue LDS-transpose -> b128 vt
// stores (kills the 2B column-scatter).
template<int MODE>
__global__ __launch_bounds__(512, 2) void gemm8(
    const __hip_bfloat16* __restrict__ A, const __hip_bfloat16* __restrict__ B,
    int nN, int cpx,
    const float* __restrict__ bq, const float* __restrict__ bk, const float* __restrict__ bv,
    __hip_bfloat16* __restrict__ qbuf, __hip_bfloat16* __restrict__ kbuf,
    __hip_bfloat16* __restrict__ vt,
    const float* __restrict__ bo, float* __restrict__ outp)
{
  constexpr int K = DMODEL;                  // 1536
  constexpr int nT = K / 64;                 // 24 K-tiles
  constexpr int nIt = nT / 2;                // 12
  __shared__ char LDSRAW[131072];
  const int tid = threadIdx.x;
  const int l = tid & 63, w = tid >> 6;
  const int lr = l & 15, lg = l >> 4;
  const int wr = w >> 2, wc = w & 3;         // 2 x 4 wave grid

  const int orig = blockIdx.x;               // bijective XCD swizzle (grid = 8*cpx)
  const int wg = (orig & 7) * cpx + (orig >> 3);
  const int m0 = (wg / nN) * 256, n0 = (wg % nN) * 256;

  const int hrow0 = tid >> 3;                 // staging row (0..63)
  const int scb0 = ((tid & 7) << 4) ^ ((hrow0 & 7) << 4);

  auto stageA = [&](int t, int half) {
    const char* s = (const char*)(A + (size_t)(m0 + half * 128) * K + t * 64);
    char* d = LDSRAW + (t & 1) * 32768 + half * 16384;
    gload16(s + (size_t)hrow0 * (K * 2) + scb0, d + tid * 16);
    gload16(s + (size_t)(hrow0 + 64) * (K * 2) + scb0, d + (tid + 512) * 16);
  };
  auto stageB = [&](int t, int half) {
    const char* s = (const char*)(B + (size_t)(n0 + half * 128) * K + t * 64);
    char* d = LDSRAW + 65536 + (t & 1) * 32768 + half * 16384;
    gload16(s + (size_t)hrow0 * (K * 2) + scb0, d + tid * 16);
    gload16(s + (size_t)(hrow0 + 64) * (K * 2) + scb0, d + (tid + 512) * 16);
  };

  f32x4 acc[8][4] = {};
  bf16x8 afr0[4][2], afr1[4][2], b0e[2][2], b0o[2][2], b1f[2][2];

  auto RA = [&](int p, int mh, bf16x8 (&dst)[4][2]) {
    const char* base = LDSRAW + p * 32768 + wr * 16384;
#pragma unroll
    for (int i = 0; i < 4; ++i) {
      int hrow = (mh * 4 + i) * 16 + lr;
#pragma unroll
      for (int ks = 0; ks < 2; ++ks)
        dst[i][ks] = *reinterpret_cast<const bf16x8*>(
            base + hrow * 128 + ((ks * 64 + lg * 16) ^ ((hrow & 7) << 4)));
    }
  };
  auto RB = [&](int p, int nh, bf16x8 (&dst)[2][2]) {
#pragma unroll
    for (int j = 0; j < 2; ++j) {
      int cbase = wc * 64 + (nh * 2 + j) * 16;
      int half = cbase >> 7;
      int hrow = (cbase & 127) + lr;
      const char* base = LDSRAW + 65536 + p * 32768 + half * 16384;
#pragma unroll
      for (int ks = 0; ks < 2; ++ks)
        dst[j][ks] = *reinterpret_cast<const bf16x8*>(
            base + hrow * 128 + ((ks * 64 + lg * 16) ^ ((hrow & 7) << 4)));
    }
  };
  auto MF = [&](int mh, int nh, bf16x8 (&a)[4][2], bf16x8 (&b)[2][2]) {
    __builtin_amdgcn_s_setprio(1);
#pragma unroll
    for (int i = 0; i < 4; ++i)
#pragma unroll
      for (int j = 0; j < 2; ++j)
#pragma unroll
        for (int ks = 0; ks < 2; ++ks)
          acc[mh * 4 + i][nh * 2 + j] = __builtin_amdgcn_mfma_f32_16x16x32_bf16(
              a[i][ks], b[j][ks], acc[mh * 4 + i][nh * 2 + j], 0, 0, 0);
    __builtin_amdgcn_s_setprio(0);
  };

#define SB0 __builtin_amdgcn_sched_barrier(0)
#define BAR __builtin_amdgcn_s_barrier()
// one tile = 4 phases; reads for quadrant i issue in phase i-1
#define TILE(p, t, b0c, b0n)                                                 \
  { /* P0: MFMA(mh0,nh0); read B(nh1) for P1 */                              \
    RB(p, 1, b1f);                                                           \
    if ((t) + 1 < nT) stageA((t) + 1, 1);                                    \
    SB0;                                                                     \
    MF(0, 0, afr0, b0c);                                                     \
    BAR;                                                                     \
    /* P1: MFMA(mh0,nh1); read A(mh1) for P2 */                              \
    RA(p, 1, afr1);                                                          \
    if ((t) + 1 < nT) stageB((t) + 1, 0);                                    \
    SB0;                                                                     \
    MF(0, 1, afr0, b1f);                                                     \
    BAR;                                                                     \
    /* P2: MFMA(mh1,nh1); tile t+1 lands here */                             \
    if ((t) + 1 < nT) stageB((t) + 1, 1);                                    \
    if ((t) + 2 < nT) stageA((t) + 2, 0);                                    \
    SB0;                                                                     \
    MF(1, 1, afr1, b1f);                                                     \
    if ((t) + 2 < nT) asm volatile("s_waitcnt vmcnt(2)" ::: "memory");       \
    else              asm volatile("s_waitcnt vmcnt(0)" ::: "memory");       \
    BAR;                                                                     \
    /* P3: MFMA(mh1,nh0); read next tile's A(mh0)+B(nh0) */                  \
    if ((t) + 1 < nT) { RA((p) ^ 1, 0, afr0); RB((p) ^ 1, 0, b0n); }         \
    SB0;                                                                     \
    MF(1, 0, afr1, b0c);                                                     \
    BAR;                                                                     \
  }

  // prologue: tile0 fully staged + A(1,0); then first quadrant's reads
  stageA(0, 0); stageA(0, 1); stageB(0, 0); stageB(0, 1); stageA(1, 0);
  asm volatile("s_waitcnt vmcnt(2)" ::: "memory");
  BAR;
  RA(0, 0, afr0); RB(0, 0, b0e);

  for (int it2 = 0; it2 < nIt; ++it2) {
    TILE(0, 2 * it2, b0e, b0o);
    TILE(1, 2 * it2 + 1, b0o, b0e);
  }
#undef TILE
#undef SB0
#undef BAR

  // ---- epilogue ----
  if (MODE == 0) {
    const int which = n0 / DMODEL;            // uniform per block
    if (which < 2) {
      // q/k: direct stores (lane-consecutive dd -> coalesced 32B chunks)
#pragma unroll
      for (int fj = 0; fj < 4; ++fj) {
        int ncol = n0 + wc * 64 + fj * 16 + lr;
        int cc = ncol - which * DMODEL;
        int hh = cc >> 7, dd = cc & 127;
        float bias = (which == 0 ? bq : bk)[cc];
#pragma unroll
        for (int fi = 0; fi < 8; ++fi)
#pragma unroll
          for (int r = 0; r < 4; ++r) {
            int rowg = m0 + wr * 128 + fi * 16 + lg * 4 + r;
            int bbb = rowg / SEQ;
            int sr = rowg - bbb * SEQ;
            __hip_bfloat16 hv = __float2bfloat16(acc[fi][fj][r] + bias);
            if (which == 0)
              qbuf[(((size_t)(bbb * NH + hh)) * SEQ + sr) * HD + dd] = hv;
            else
              kbuf[(((size_t)(bbb * NH + hh)) * SEQ + sr) * HD + dd] = hv;
          }
      }
    } else {
      // v: LDS transpose bounce -> coalesced b128 stores to vt[d][s]
      __syncthreads();                        // K-loop LDS dead; reuse LDSRAW
      const int cc0 = n0 - 2 * DMODEL;
#pragma unroll
      for (int fj = 0; fj < 4; ++fj) {
        int d_loc = wc * 64 + fj * 16 + lr;   // 0..255
        float bias = bv[cc0 + d_loc];
#pragma unroll
        for (int fi = 0; fi < 8; ++fi)
#pragma unroll
          for (int r = 0; r < 4; ++r) {
            int s_loc = wr * 128 + fi * 16 + lg * 4 + r;
            *reinterpret_cast<short*>(LDSRAW + d_loc * 512 +
                ((s_loc * 2) ^ ((d_loc & 7) << 4))) = f2bf(acc[fi][fj][r] + bias);
          }
      }
      __syncthreads();
      const int bbb = m0 / SEQ;               // 1792 = 7*256: m-tiles never span batch
      const int sr0 = m0 - bbb * SEQ;
#pragma unroll
      for (int c = 0; c < 16; ++c) {
        int g = c * 512 + tid;                // 16B chunk id in [0,8192)
        int d = g >> 5;                       // 32 chunks per 512B d-row
        int sb = (g & 31) << 4;               // byte offset within row
        bf16x8 vvv = *reinterpret_cast<const bf16x8*>(
            LDSRAW + d * 512 + (sb ^ ((d & 7) << 4)));
        int ddg = cc0 + d, hh = ddg >> 7, dd = ddg & 127;
        *reinterpret_cast<bf16x8*>(
            &vt[(((size_t)(bbb * NH + hh)) * HD + dd) * SEQ + sr0 + (sb >> 1)]) = vvv;
      }
    }
  } else {
#pragma unroll
    for (int fj = 0; fj < 4; ++fj) {
      int ncol = n0 + wc * 64 + fj * 16 + lr;
      float bias = bo[ncol];
#pragma unroll
      for (int fi = 0; fi < 8; ++fi)
#pragma unroll
        for (int r = 0; r < 4; ++r) {
          int rowg = m0 + wr * 128 + fi * 16 + lg * 4 + r;
          outp[(size_t)rowg * DMODEL + ncol] = acc[fi][fj][r] + bias;
        }
    }
  }
}

// ---------- RMSNorm (full-D) + 3D-grid RoPE, in-place on q,k ----------
__global__ __launch_bounds__(256) void rmsrope_kernel(
    __hip_bfloat16* __restrict__ qb, __hip_bfloat16* __restrict__ kb,
    const float* __restrict__ gq, const float* __restrict__ gk,
    const float* __restrict__ fc, const float* __restrict__ fs,
    const int* __restrict__ gsz, const int* __restrict__ nmod)
{
  const int bs = blockIdx.x;
  const int b = bs / SEQ, s = bs - b * SEQ;
  const int t = threadIdx.x;
  const int f = gsz[0], h = gsz[1], wd = gsz[2];
  const int mm = nmod[0];
  const int seq_per = f * h * wd;
  int total_len = seq_per * mm; if (total_len > SEQ) total_len = SEQ;
  const bool dorope = s < total_len;
  int fi = 0, hi2 = 0, wi = 0;
  if (dorope) {
    int p = s % seq_per;
    fi = p / (h * wd);
    int rem = p - fi * (h * wd);
    hi2 = rem / wd;
    wi = rem - hi2 * wd;
  }
  float qv[3][2], kv[3][2];
  float sq = 0.f, sk = 0.f;
#pragma unroll
  for (int r = 0; r < 3; ++r) {
    int pi = t + r * 256;
    int head = pi >> 6;
    int dd = (pi & 63) * 2;
    size_t addr = (((size_t)(b * NH + head)) * SEQ + s) * HD + dd;
    __hip_bfloat162 q2 = *reinterpret_cast<const __hip_bfloat162*>(&qb[addr]);
    __hip_bfloat162 k2 = *reinterpret_cast<const __hip_bfloat162*>(&kb[addr]);
    qv[r][0] = __bfloat162float(q2.x); qv[r][1] = __bfloat162float(q2.y);
    kv[r][0] = __bfloat162float(k2.x); kv[r][1] = __bfloat162float(k2.y);
    sq += qv[r][0] * qv[r][0] + qv[r][1] * qv[r][1];
    sk += kv[r][0] * kv[r][0] + kv[r][1] * kv[r][1];
  }
#pragma unroll
  for (int off = 1; off < 64; off <<= 1) {
    sq += __shfl_xor(sq, off);
    sk += __shfl_xor(sk, off);
  }
  __shared__ float red[2][4];
  if ((t & 63) == 0) { red[0][t >> 6] = sq; red[1][t >> 6] = sk; }
  __syncthreads();
  float tq = red[0][0] + red[0][1] + red[0][2] + red[0][3];
  float tk = red[1][0] + red[1][1] + red[1][2] + red[1][3];
  float rq = rsqrtf(tq * (1.0f / DMODEL) + 1e-6f);
  float rk = rsqrtf(tk * (1.0f / DMODEL) + 1e-6f);
  const float scale = 0.08838834764831845f; // 1/sqrt(128), folded into q
#pragma unroll
  for (int r = 0; r < 3; ++r) {
    int pi = t + r * 256;
    int head = pi >> 6;
    int dd = (pi & 63) * 2;
    int col = pi * 2;
    size_t addr = (((size_t)(b * NH + head)) * SEQ + s) * HD + dd;
    float q0 = qv[r][0] * rq * gq[col], q1 = qv[r][1] * rq * gq[col + 1];
    float k0 = kv[r][0] * rk * gk[col], k1 = kv[r][1] * rk * gk[col + 1];
    if (dorope) {
      int j = pi & 63;
      int row = (j < 22) ? fi : (j < 43) ? hi2 : wi;
      float co = fc[row * 64 + j], si = fs[row * 64 + j];
      float a;
      a = q0 * co - q1 * si; q1 = q0 * si + q1 * co; q0 = a;
      a = k0 * co - k1 * si; k1 = k0 * si + k1 * co; k0 = a;
    }
    q0 *= scale; q1 *= scale;
    __hip_bfloat162 oq, ok;
    oq.x = __float2bfloat16(q0); oq.y = __float2bfloat16(q1);
    ok.x = __float2bfloat16(k0); ok.y = __float2bfloat16(k1);
    *reinterpret_cast<__hip_bfloat162*>(&qb[addr]) = oq;
    *reinterpret_cast<__hip_bfloat162*>(&kb[addr]) = ok;
  }
}

// ---------- flash attention v10: 4 waves x QBLK=32, K AND V LDS-staged ----------
__global__ __launch_bounds__(256, 2) void attn_kernel(
    const __hip_bfloat16* __restrict__ qb, const __hip_bfloat16* __restrict__ kbuf,
    const __hip_bfloat16* __restrict__ vt, const int* __restrict__ seq_lens,
    __hip_bfloat16* __restrict__ ob)
{
  const int orig = blockIdx.x;
  const int wg = (orig & 7) * 84 + (orig >> 3);
  const int bh = wg / 14, qt = wg % 14;
  const int bbb = bh / NH, hh = bh - bbb * NH;
  const int tid = threadIdx.x;
  const int w = tid >> 6, l = tid & 63;
  const int lq = l & 31, h = l >> 5;
  const int sl = seq_lens[bbb];
  const __hip_bfloat16* Q = qb + (size_t)bh * SEQ * HD;
  const char* Kc = (const char*)(kbuf + (size_t)bh * SEQ * HD);
  const __hip_bfloat16* Vp = vt + (size_t)bh * HD * SEQ;   // [128][1792]
  const int q0 = qt * 128 + w * 32;

  __shared__ __hip_bfloat16 Kt[2][64 * 128];   // K tile, 256B rows, ^((row&7)<<4)
  __shared__ __hip_bfloat16 Vt[2][128 * 64];   // V^T tile [d][k], 128B rows, ^((row&7)<<4)

  bf16x8 qf[8];
#pragma unroll
  for (int kc = 0; kc < 8; ++kc)
    qf[kc] = *reinterpret_cast<const bf16x8*>(
        &Q[(size_t)(q0 + lq) * HD + kc * 16 + h * 8]);

  f32x16 oacc[4] = {};                          // O[q_off][d0*32+lq]
  float m = -3e38f, ll = 0.f;                   // per-lane q-row softmax state

  const int nkt = (sl + 63) >> 6;

  auto stageK = [&](int buf, int k0) {
    char* Lb = (char*)&Kt[buf][0];
#pragma unroll
    for (int q2 = 0; q2 < 4; ++q2) {
      int chunk = q2 * 256 + tid;
      int row = chunk >> 4;
      int cb = (chunk & 15) << 4;
      int scb = cb ^ ((row & 7) << 4);
      gload16(Kc + (size_t)(k0 + row) * 256 + scb, Lb + chunk * 16);
    }
  };
  auto stageV = [&](int buf, int k0) {
    char* Lb = (char*)&Vt[buf][0];
#pragma unroll
    for (int q2 = 0; q2 < 4; ++q2) {
      int chunk = q2 * 256 + tid;
      int row = chunk >> 3;
      int cb = (chunk & 7) << 4;
      int scb = cb ^ ((row & 7) << 4);
      gload16(Vp + (size_t)row * SEQ + k0 + (scb >> 1), Lb + chunk * 16);
    }
  };

  stageK(0, 0);
  stageV(0, 0);
  for (int kt = 0; kt < nkt; ++kt) {
    __syncthreads();
    const int k0 = kt * 64;
    if (kt + 1 < nkt) { stageK((kt + 1) & 1, k0 + 64); stageV((kt + 1) & 1, k0 + 64); }
    const char* Kl = (const char*)&Kt[kt & 1][0];
    const char* Vl = (const char*)&Vt[kt & 1][0];

    f32x16 sa[2] = {};
#pragma unroll
    for (int cb = 0; cb < 2; ++cb) {
      int row = cb * 32 + lq;
      int swz = (row & 7) << 4;
#pragma unroll
      for (int kc = 0; kc < 8; ++kc) {
        bf16x8 kf = *reinterpret_cast<const bf16x8*>(
            Kl + row * 256 + ((kc * 32 + h * 16) ^ swz));
        sa[cb] = __builtin_amdgcn_mfma_f32_32x32x16_bf16(kf, qf[kc], sa[cb], 0, 0, 0);
      }
    }

    if (k0 + 64 > sl) {
#pragma unroll
      for (int cb = 0; cb < 2; ++cb)
#pragma unroll
        for (int r = 0; r < 16; ++r) {
          int kg = k0 + cb * 32 + (r & 3) + 8 * (r >> 2) + 4 * h;
          if (kg >= sl) sa[cb][r] = -3e38f;
        }
    }

    float mx = -3e38f;
#pragma unroll
    for (int cb = 0; cb < 2; ++cb)
#pragma unroll
      for (int r = 0; r < 16; ++r) mx = fmaxf(mx, sa[cb][r]);
    mx = fmaxf(mx, __shfl_xor(mx, 32));

    if (__any(mx - m > 8.f)) {                  // defer-max (T13)
      float mn = fmaxf(m, mx);
      float alpha = __expf(m - mn);
      m = mn;
      ll *= alpha;
#pragma unroll
      for (int r = 0; r < 16; ++r) {
        float ar = __shfl(alpha, (r & 3) + 8 * (r >> 2) + 4 * h);
#pragma unroll
        for (int d0 = 0; d0 < 4; ++d0) oacc[d0][r] *= ar;
      }
    }

    float rs = 0.f;
#pragma unroll
    for (int cb = 0; cb < 2; ++cb)
#pragma unroll
      for (int r = 0; r < 16; ++r) {
        float e = __expf(sa[cb][r] - m);
        sa[cb][r] = e;
        rs += e;
      }
    rs += __shfl_xor(rs, 32);
    ll += rs;

#pragma unroll
    for (int c = 0; c < 4; ++c) {
      const int cb = c >> 1, r0 = 8 * (c & 1);
      unsigned A01 = pack2(sa[cb][r0],     sa[cb][r0 + 1]);
      unsigned A23 = pack2(sa[cb][r0 + 2], sa[cb][r0 + 3]);
      unsigned B01 = pack2(sa[cb][r0 + 4], sa[cb][r0 + 5]);
      unsigned B23 = pack2(sa[cb][r0 + 6], sa[cb][r0 + 7]);
      unsigned s1 = __shfl_xor(h ? A01 : B01, 32);
      unsigned s2 = __shfl_xor(h ? A23 : B23, 32);
      int4 wv;
      wv.x = (int)(h ? s1 : A01);
      wv.y = (int)(h ? s2 : A23);
      wv.z = (int)(h ? B01 : s1);
      wv.w = (int)(h ? B23 : s2);
      bf16x8 pa = *reinterpret_cast<bf16x8*>(&wv);
#pragma unroll
      for (int d0 = 0; d0 < 4; ++d0) {
        int vr = d0 * 32 + lq;
        bf16x8 vv = *reinterpret_cast<const bf16x8*>(
            Vl + vr * 128 + ((c * 32 + h * 16) ^ ((vr & 7) << 4)));
        oacc[d0] = __builtin_amdgcn_mfma_f32_32x32x16_bf16(pa, vv, oacc[d0], 0, 0, 0);
      }
    }
  }

  float invl = 1.0f / ll;
#pragma unroll
  for (int r = 0; r < 16; ++r) {
    int qoff = (r & 3) + 8 * (r >> 2) + 4 * h;
    float ir = __shfl(invl, qoff);
    int qrow = q0 + qoff;
#pragma unroll
    for (int d0 = 0; d0 < 4; ++d0)
      ob[((size_t)bbb * SEQ + qrow) * DMODEL + hh * HD + d0 * 32 + lq] =
          __float2bfloat16(oacc[d0][r] * ir);
  }
}

// ---------- launch ----------
extern "C" void kernel_launch(void* const* d_in, const int* in_sizes, int n_in,
                              void* d_out, int out_size, void* d_ws, size_t ws_size,
                              hipStream_t stream) {
  const float* x   = (const float*)d_in[0];
  const int* seq_lens   = (const int*)d_in[1];
  const int* grid_sizes = (const int*)d_in[2];
  const float* fc  = (const float*)d_in[3];
  const float* fs  = (const float*)d_in[4];
  const float* Wq  = (const float*)d_in[5];
  const float* bq  = (const float*)d_in[6];
  const float* Wk  = (const float*)d_in[7];
  const float* bk  = (const float*)d_in[8];
  const float* Wv  = (const float*)d_in[9];
  const float* bv  = (const float*)d_in[10];
  const float* Wo  = (const float*)d_in[11];
  const float* bo  = (const float*)d_in[12];
  const float* gq  = (const float*)d_in[13];
  const float* gk  = (const float*)d_in[14];
  const int* nmod  = (const int*)d_in[15];
  float* out = (float*)d_out;

  char* ws = (char*)d_ws;
  __hip_bfloat16* xb   = (__hip_bfloat16*)(ws + 0);           // [7168][1536]
  __hip_bfloat16* wb   = (__hip_bfloat16*)(ws + 22020096);    // [4608][1536]
  __hip_bfloat16* wob  = (__hip_bfloat16*)(ws + 36175872);    // [1536][1536]
  __hip_bfloat16* qbuf = (__hip_bfloat16*)(ws + 40894464);    // [48][1792][128]
  __hip_bfloat16* kbuf = (__hip_bfloat16*)(ws + 62914560);    // [48][1792][128]
  __hip_bfloat16* vtb  = (__hip_bfloat16*)(ws + 84934656);    // [48][128][1792]
  __hip_bfloat16* ob   = xb;                                  // O reuses xb region

  cast_all_kernel<<<(5111808 + 255) / 256, 256, 0, stream>>>(x, Wq, Wk, Wv, Wo, xb, wb, wob);

  // QKV: M=7168 (28 tiles) x N=4608 (18 tiles) -> 504 = 8*63
  gemm8<0><<<504, 512, 0, stream>>>(xb, wb, 18, 63, bq, bk, bv,
                                    qbuf, kbuf, vtb, nullptr, nullptr);
  rmsrope_kernel<<<7168, 256, 0, stream>>>(qbuf, kbuf, gq, gk, fc, fs, grid_sizes, nmod);
  attn_kernel<<<672, 256, 0, stream>>>(qbuf, kbuf, vtb, seq_lens, ob);
  // out-proj: M=7168 (28) x N=1536 (6 tiles) -> 168 = 8*21
  gemm8<1><<<168, 512, 0, stream>>>(ob, wob, 6, 21, nullptr, nullptr, nullptr,
                                    nullptr, nullptr, nullptr, bo, out);
}

// Round 13
// 319.680 us; speedup vs baseline: 1.4959x; 1.0221x over previous
//
#include <hip/hip_runtime.h>
#include <hip/hip_bf16.h>

typedef short bf16x8 __attribute__((ext_vector_type(8)));
typedef float f32x4 __attribute__((ext_vector_type(4)));
typedef float f32x16 __attribute__((ext_vector_type(16)));

#define NH 12
#define SEQ 1792
#define DMODEL 1536
#define HD 128

static __device__ __forceinline__ void gload16(const void* g, void* l) {
  __builtin_amdgcn_global_load_lds((const __attribute__((address_space(1))) void*)g,
                                   (__attribute__((address_space(3))) void*)l, 16, 0, 0);
}

static __device__ __forceinline__ short f2bf(float x) {
  __hip_bfloat16 h = __float2bfloat16(x);
  return *reinterpret_cast<short*>(&h);
}

static __device__ __forceinline__ unsigned pack2(float lo, float hi) {
  unsigned a = (unsigned)(unsigned short)f2bf(lo);
  unsigned b = (unsigned)(unsigned short)f2bf(hi);
  return a | (b << 16);
}

// ---------- fused fp32 -> bf16 cast for x + Wq + Wk + Wv + Wo (one launch) ----------
__global__ __launch_bounds__(256) void cast_all_kernel(
    const float* __restrict__ x, const float* __restrict__ wq, const float* __restrict__ wk,
    const float* __restrict__ wv, const float* __restrict__ wo,
    __hip_bfloat16* __restrict__ xb, __hip_bfloat16* __restrict__ wb,
    __hip_bfloat16* __restrict__ wob) {
  int i = blockIdx.x * 256 + threadIdx.x;
  const float* src; __hip_bfloat16* dst; int j;
  if (i < 2752512)      { src = x;  dst = xb;            j = i; }
  else if (i < 3342336) { src = wq; dst = wb;            j = i - 2752512; }
  else if (i < 3932160) { src = wk; dst = wb + 2359296;  j = i - 3342336; }
  else if (i < 4521984) { src = wv; dst = wb + 4718592;  j = i - 3932160; }
  else if (i < 5111808) { src = wo; dst = wob;           j = i - 4521984; }
  else return;
  float4 v = reinterpret_cast<const float4*>(src)[j];
  short4 r;
  r.x = f2bf(v.x); r.y = f2bf(v.y); r.z = f2bf(v.z); r.w = f2bf(v.w);
  reinterpret_cast<short4*>(dst)[j] = r;
}

// ---------- 256x256 bf16 GEMM, 8-phase, reads pipelined ONE PHASE AHEAD ----------
template<int MODE>
__global__ __launch_bounds__(512, 2) void gemm8(
    const __hip_bfloat16* __restrict__ A, const __hip_bfloat16* __restrict__ B,
    int nN, int cpx,
    const float* __restrict__ bq, const float* __restrict__ bk, const float* __restrict__ bv,
    __hip_bfloat16* __restrict__ qbuf, __hip_bfloat16* __restrict__ kbuf,
    __hip_bfloat16* __restrict__ vt,
    const float* __restrict__ bo, float* __restrict__ outp)
{
  constexpr int K = DMODEL;                  // 1536
  constexpr int nT = K / 64;                 // 24 K-tiles
  constexpr int nIt = nT / 2;                // 12
  __shared__ char LDSRAW[131072];
  const int tid = threadIdx.x;
  const int l = tid & 63, w = tid >> 6;
  const int lr = l & 15, lg = l >> 4;
  const int wr = w >> 2, wc = w & 3;         // 2 x 4 wave grid

  const int orig = blockIdx.x;               // bijective XCD swizzle (grid = 8*cpx)
  const int wg = (orig & 7) * cpx + (orig >> 3);
  const int m0 = (wg / nN) * 256, n0 = (wg % nN) * 256;

  const int hrow0 = tid >> 3;                 // staging row (0..63)
  const int scb0 = ((tid & 7) << 4) ^ ((hrow0 & 7) << 4);

  auto stageA = [&](int t, int half) {
    const char* s = (const char*)(A + (size_t)(m0 + half * 128) * K + t * 64);
    char* d = LDSRAW + (t & 1) * 32768 + half * 16384;
    gload16(s + (size_t)hrow0 * (K * 2) + scb0, d + tid * 16);
    gload16(s + (size_t)(hrow0 + 64) * (K * 2) + scb0, d + (tid + 512) * 16);
  };
  auto stageB = [&](int t, int half) {
    const char* s = (const char*)(B + (size_t)(n0 + half * 128) * K + t * 64);
    char* d = LDSRAW + 65536 + (t & 1) * 32768 + half * 16384;
    gload16(s + (size_t)hrow0 * (K * 2) + scb0, d + tid * 16);
    gload16(s + (size_t)(hrow0 + 64) * (K * 2) + scb0, d + (tid + 512) * 16);
  };

  f32x4 acc[8][4] = {};
  bf16x8 afr0[4][2], afr1[4][2], b0e[2][2], b0o[2][2], b1f[2][2];

  auto RA = [&](int p, int mh, bf16x8 (&dst)[4][2]) {
    const char* base = LDSRAW + p * 32768 + wr * 16384;
#pragma unroll
    for (int i = 0; i < 4; ++i) {
      int hrow = (mh * 4 + i) * 16 + lr;
#pragma unroll
      for (int ks = 0; ks < 2; ++ks)
        dst[i][ks] = *reinterpret_cast<const bf16x8*>(
            base + hrow * 128 + ((ks * 64 + lg * 16) ^ ((hrow & 7) << 4)));
    }
  };
  auto RB = [&](int p, int nh, bf16x8 (&dst)[2][2]) {
#pragma unroll
    for (int j = 0; j < 2; ++j) {
      int cbase = wc * 64 + (nh * 2 + j) * 16;
      int half = cbase >> 7;
      int hrow = (cbase & 127) + lr;
      const char* base = LDSRAW + 65536 + p * 32768 + half * 16384;
#pragma unroll
      for (int ks = 0; ks < 2; ++ks)
        dst[j][ks] = *reinterpret_cast<const bf16x8*>(
            base + hrow * 128 + ((ks * 64 + lg * 16) ^ ((hrow & 7) << 4)));
    }
  };
  auto MF = [&](int mh, int nh, bf16x8 (&a)[4][2], bf16x8 (&b)[2][2]) {
    __builtin_amdgcn_s_setprio(1);
#pragma unroll
    for (int i = 0; i < 4; ++i)
#pragma unroll
      for (int j = 0; j < 2; ++j)
#pragma unroll
        for (int ks = 0; ks < 2; ++ks)
          acc[mh * 4 + i][nh * 2 + j] = __builtin_amdgcn_mfma_f32_16x16x32_bf16(
              a[i][ks], b[j][ks], acc[mh * 4 + i][nh * 2 + j], 0, 0, 0);
    __builtin_amdgcn_s_setprio(0);
  };

#define SB0 __builtin_amdgcn_sched_barrier(0)
#define BAR __builtin_amdgcn_s_barrier()
#define TILE(p, t, b0c, b0n)                                                 \
  { RB(p, 1, b1f);                                                           \
    if ((t) + 1 < nT) stageA((t) + 1, 1);                                    \
    SB0;                                                                     \
    MF(0, 0, afr0, b0c);                                                     \
    BAR;                                                                     \
    RA(p, 1, afr1);                                                          \
    if ((t) + 1 < nT) stageB((t) + 1, 0);                                    \
    SB0;                                                                     \
    MF(0, 1, afr0, b1f);                                                     \
    BAR;                                                                     \
    if ((t) + 1 < nT) stageB((t) + 1, 1);                                    \
    if ((t) + 2 < nT) stageA((t) + 2, 0);                                    \
    SB0;                                                                     \
    MF(1, 1, afr1, b1f);                                                     \
    if ((t) + 2 < nT) asm volatile("s_waitcnt vmcnt(2)" ::: "memory");       \
    else              asm volatile("s_waitcnt vmcnt(0)" ::: "memory");       \
    BAR;                                                                     \
    if ((t) + 1 < nT) { RA((p) ^ 1, 0, afr0); RB((p) ^ 1, 0, b0n); }         \
    SB0;                                                                     \
    MF(1, 0, afr1, b0c);                                                     \
    BAR;                                                                     \
  }

  stageA(0, 0); stageA(0, 1); stageB(0, 0); stageB(0, 1); stageA(1, 0);
  asm volatile("s_waitcnt vmcnt(2)" ::: "memory");
  BAR;
  RA(0, 0, afr0); RB(0, 0, b0e);

  for (int it2 = 0; it2 < nIt; ++it2) {
    TILE(0, 2 * it2, b0e, b0o);
    TILE(1, 2 * it2 + 1, b0o, b0e);
  }
#undef TILE
#undef SB0
#undef BAR

  // ---- epilogue ----
  if (MODE == 0) {
    const int which = n0 / DMODEL;            // uniform per block
    if (which < 2) {
#pragma unroll
      for (int fj = 0; fj < 4; ++fj) {
        int ncol = n0 + wc * 64 + fj * 16 + lr;
        int cc = ncol - which * DMODEL;
        int hh = cc >> 7, dd = cc & 127;
        float bias = (which == 0 ? bq : bk)[cc];
#pragma unroll
        for (int fi = 0; fi < 8; ++fi)
#pragma unroll
          for (int r = 0; r < 4; ++r) {
            int rowg = m0 + wr * 128 + fi * 16 + lg * 4 + r;
            int bbb = rowg / SEQ;
            int sr = rowg - bbb * SEQ;
            __hip_bfloat16 hv = __float2bfloat16(acc[fi][fj][r] + bias);
            if (which == 0)
              qbuf[(((size_t)(bbb * NH + hh)) * SEQ + sr) * HD + dd] = hv;
            else
              kbuf[(((size_t)(bbb * NH + hh)) * SEQ + sr) * HD + dd] = hv;
          }
      }
    } else {
      // v: LDS transpose bounce -> coalesced b128 stores to vt[d][s]
      __syncthreads();
      const int cc0 = n0 - 2 * DMODEL;
#pragma unroll
      for (int fj = 0; fj < 4; ++fj) {
        int d_loc = wc * 64 + fj * 16 + lr;   // 0..255
        float bias = bv[cc0 + d_loc];
#pragma unroll
        for (int fi = 0; fi < 8; ++fi)
#pragma unroll
          for (int r = 0; r < 4; ++r) {
            int s_loc = wr * 128 + fi * 16 + lg * 4 + r;
            *reinterpret_cast<short*>(LDSRAW + d_loc * 512 +
                ((s_loc * 2) ^ ((d_loc & 7) << 4))) = f2bf(acc[fi][fj][r] + bias);
          }
      }
      __syncthreads();
      const int bbb = m0 / SEQ;
      const int sr0 = m0 - bbb * SEQ;
#pragma unroll
      for (int c = 0; c < 16; ++c) {
        int g = c * 512 + tid;
        int d = g >> 5;
        int sb = (g & 31) << 4;
        bf16x8 vvv = *reinterpret_cast<const bf16x8*>(
            LDSRAW + d * 512 + (sb ^ ((d & 7) << 4)));
        int ddg = cc0 + d, hh = ddg >> 7, dd = ddg & 127;
        *reinterpret_cast<bf16x8*>(
            &vt[(((size_t)(bbb * NH + hh)) * HD + dd) * SEQ + sr0 + (sb >> 1)]) = vvv;
      }
    }
  } else {
#pragma unroll
    for (int fj = 0; fj < 4; ++fj) {
      int ncol = n0 + wc * 64 + fj * 16 + lr;
      float bias = bo[ncol];
#pragma unroll
      for (int fi = 0; fi < 8; ++fi)
#pragma unroll
        for (int r = 0; r < 4; ++r) {
          int rowg = m0 + wr * 128 + fi * 16 + lg * 4 + r;
          outp[(size_t)rowg * DMODEL + ncol] = acc[fi][fj][r] + bias;
        }
    }
  }
}

// ---------- RMSNorm (full-D) + 3D-grid RoPE, in-place on q,k ----------
__global__ __launch_bounds__(256) void rmsrope_kernel(
    __hip_bfloat16* __restrict__ qb, __hip_bfloat16* __restrict__ kb,
    const float* __restrict__ gq, const float* __restrict__ gk,
    const float* __restrict__ fc, const float* __restrict__ fs,
    const int* __restrict__ gsz, const int* __restrict__ nmod)
{
  const int bs = blockIdx.x;
  const int b = bs / SEQ, s = bs - b * SEQ;
  const int t = threadIdx.x;
  const int f = gsz[0], h = gsz[1], wd = gsz[2];
  const int mm = nmod[0];
  const int seq_per = f * h * wd;
  int total_len = seq_per * mm; if (total_len > SEQ) total_len = SEQ;
  const bool dorope = s < total_len;
  int fi = 0, hi2 = 0, wi = 0;
  if (dorope) {
    int p = s % seq_per;
    fi = p / (h * wd);
    int rem = p - fi * (h * wd);
    hi2 = rem / wd;
    wi = rem - hi2 * wd;
  }
  float qv[3][2], kv[3][2];
  float sq = 0.f, sk = 0.f;
#pragma unroll
  for (int r = 0; r < 3; ++r) {
    int pi = t + r * 256;
    int head = pi >> 6;
    int dd = (pi & 63) * 2;
    size_t addr = (((size_t)(b * NH + head)) * SEQ + s) * HD + dd;
    __hip_bfloat162 q2 = *reinterpret_cast<const __hip_bfloat162*>(&qb[addr]);
    __hip_bfloat162 k2 = *reinterpret_cast<const __hip_bfloat162*>(&kb[addr]);
    qv[r][0] = __bfloat162float(q2.x); qv[r][1] = __bfloat162float(q2.y);
    kv[r][0] = __bfloat162float(k2.x); kv[r][1] = __bfloat162float(k2.y);
    sq += qv[r][0] * qv[r][0] + qv[r][1] * qv[r][1];
    sk += kv[r][0] * kv[r][0] + kv[r][1] * kv[r][1];
  }
#pragma unroll
  for (int off = 1; off < 64; off <<= 1) {
    sq += __shfl_xor(sq, off);
    sk += __shfl_xor(sk, off);
  }
  __shared__ float red[2][4];
  if ((t & 63) == 0) { red[0][t >> 6] = sq; red[1][t >> 6] = sk; }
  __syncthreads();
  float tq = red[0][0] + red[0][1] + red[0][2] + red[0][3];
  float tk = red[1][0] + red[1][1] + red[1][2] + red[1][3];
  float rq = rsqrtf(tq * (1.0f / DMODEL) + 1e-6f);
  float rk = rsqrtf(tk * (1.0f / DMODEL) + 1e-6f);
  const float scale = 0.08838834764831845f; // 1/sqrt(128), folded into q
#pragma unroll
  for (int r = 0; r < 3; ++r) {
    int pi = t + r * 256;
    int head = pi >> 6;
    int dd = (pi & 63) * 2;
    int col = pi * 2;
    size_t addr = (((size_t)(b * NH + head)) * SEQ + s) * HD + dd;
    float q0 = qv[r][0] * rq * gq[col], q1 = qv[r][1] * rq * gq[col + 1];
    float k0 = kv[r][0] * rk * gk[col], k1 = kv[r][1] * rk * gk[col + 1];
    if (dorope) {
      int j = pi & 63;
      int row = (j < 22) ? fi : (j < 43) ? hi2 : wi;
      float co = fc[row * 64 + j], si = fs[row * 64 + j];
      float a;
      a = q0 * co - q1 * si; q1 = q0 * si + q1 * co; q0 = a;
      a = k0 * co - k1 * si; k1 = k0 * si + k1 * co; k0 = a;
    }
    q0 *= scale; q1 *= scale;
    __hip_bfloat162 oq, ok;
    oq.x = __float2bfloat16(q0); oq.y = __float2bfloat16(q1);
    ok.x = __float2bfloat16(k0); ok.y = __float2bfloat16(k1);
    *reinterpret_cast<__hip_bfloat162*>(&qb[addr]) = oq;
    *reinterpret_cast<__hip_bfloat162*>(&kb[addr]) = ok;
  }
}

// ---------- flash attention v11: K dbuf + V SINGLE-buffer (48 KB -> 3 blocks/CU) ----------
// Per tile: top __syncthreads (drains prev K prefetch; V(kt-1) reads done) ->
// stageV(kt) then stageK(kt+1) -> QK^T+softmax (covers V latency) ->
// counted vmcnt(4) [K prefetch stays in flight] + raw s_barrier -> PV.
// 672 blocks / 768 slots = single round (R12 ran 1.31 rounds at 2 blocks/CU).
__global__ __launch_bounds__(256, 2) void attn_kernel(
    const __hip_bfloat16* __restrict__ qb, const __hip_bfloat16* __restrict__ kbuf,
    const __hip_bfloat16* __restrict__ vt, const int* __restrict__ seq_lens,
    __hip_bfloat16* __restrict__ ob)
{
  const int orig = blockIdx.x;
  const int wg = (orig & 7) * 84 + (orig >> 3);
  const int bh = wg / 14, qt = wg % 14;
  const int bbb = bh / NH, hh = bh - bbb * NH;
  const int tid = threadIdx.x;
  const int w = tid >> 6, l = tid & 63;
  const int lq = l & 31, h = l >> 5;
  const int sl = seq_lens[bbb];
  const __hip_bfloat16* Q = qb + (size_t)bh * SEQ * HD;
  const char* Kc = (const char*)(kbuf + (size_t)bh * SEQ * HD);
  const __hip_bfloat16* Vp = vt + (size_t)bh * HD * SEQ;   // [128][1792]
  const int q0 = qt * 128 + w * 32;

  __shared__ __hip_bfloat16 Kt[2][64 * 128];   // 32 KB, 256B rows, ^((row&7)<<4)
  __shared__ __hip_bfloat16 Vt[128 * 64];      // 16 KB single buffer, 128B rows

  bf16x8 qf[8];
#pragma unroll
  for (int kc = 0; kc < 8; ++kc)
    qf[kc] = *reinterpret_cast<const bf16x8*>(
        &Q[(size_t)(q0 + lq) * HD + kc * 16 + h * 8]);

  f32x16 oacc[4] = {};                          // O[q_off][d0*32+lq]
  float m = -3e38f, ll = 0.f;                   // per-lane q-row softmax state

  const int nkt = (sl + 63) >> 6;

  auto stageK = [&](int buf, int k0) {
    char* Lb = (char*)&Kt[buf][0];
#pragma unroll
    for (int q2 = 0; q2 < 4; ++q2) {
      int chunk = q2 * 256 + tid;
      int row = chunk >> 4;
      int cb = (chunk & 15) << 4;
      int scb = cb ^ ((row & 7) << 4);
      gload16(Kc + (size_t)(k0 + row) * 256 + scb, Lb + chunk * 16);
    }
  };
  auto stageV = [&](int k0) {
    char* Lb = (char*)&Vt[0];
#pragma unroll
    for (int q2 = 0; q2 < 4; ++q2) {
      int chunk = q2 * 256 + tid;
      int row = chunk >> 3;
      int cb = (chunk & 7) << 4;
      int scb = cb ^ ((row & 7) << 4);
      gload16(Vp + (size_t)row * SEQ + k0 + (scb >> 1), Lb + chunk * 16);
    }
  };

  stageK(0, 0);
  for (int kt = 0; kt < nkt; ++kt) {
    __syncthreads();                            // K(kt) landed everywhere; Vt reads done
    const int k0 = kt * 64;
    stageV(k0);                                 // V first (oldest in vmcnt queue)
    const bool pf = (kt + 1 < nkt);
    if (pf) stageK((kt + 1) & 1, k0 + 64);      // K prefetch after
    const char* Kl = (const char*)&Kt[kt & 1][0];
    const char* Vl = (const char*)&Vt[0];

    // swapped QK^T: S^T[k][q], 16 ds_read_b128 + 16 mfma_32x32x16
    f32x16 sa[2] = {};
#pragma unroll
    for (int cb = 0; cb < 2; ++cb) {
      int row = cb * 32 + lq;
      int swz = (row & 7) << 4;
#pragma unroll
      for (int kc = 0; kc < 8; ++kc) {
        bf16x8 kf = *reinterpret_cast<const bf16x8*>(
            Kl + row * 256 + ((kc * 32 + h * 16) ^ swz));
        sa[cb] = __builtin_amdgcn_mfma_f32_32x32x16_bf16(kf, qf[kc], sa[cb], 0, 0, 0);
      }
    }

    // mask tail (rare)
    if (k0 + 64 > sl) {
#pragma unroll
      for (int cb = 0; cb < 2; ++cb)
#pragma unroll
        for (int r = 0; r < 16; ++r) {
          int kg = k0 + cb * 32 + (r & 3) + 8 * (r >> 2) + 4 * h;
          if (kg >= sl) sa[cb][r] = -3e38f;
        }
    }

    // in-register online softmax
    float mx = -3e38f;
#pragma unroll
    for (int cb = 0; cb < 2; ++cb)
#pragma unroll
      for (int r = 0; r < 16; ++r) mx = fmaxf(mx, sa[cb][r]);
    mx = fmaxf(mx, __shfl_xor(mx, 32));

    if (__any(mx - m > 8.f)) {                  // defer-max (T13)
      float mn = fmaxf(m, mx);
      float alpha = __expf(m - mn);
      m = mn;
      ll *= alpha;
#pragma unroll
      for (int r = 0; r < 16; ++r) {
        float ar = __shfl(alpha, (r & 3) + 8 * (r >> 2) + 4 * h);
#pragma unroll
        for (int d0 = 0; d0 < 4; ++d0) oacc[d0][r] *= ar;
      }
    }

    float rs = 0.f;
#pragma unroll
    for (int cb = 0; cb < 2; ++cb)
#pragma unroll
      for (int r = 0; r < 16; ++r) {
        float e = __expf(sa[cb][r] - m);
        sa[cb][r] = e;
        rs += e;
      }
    rs += __shfl_xor(rs, 32);
    ll += rs;

    // V(kt) visibility: my V retired (counted) + all waves' V retired (barrier)
    if (pf) asm volatile("s_waitcnt vmcnt(4)" ::: "memory");
    else    asm volatile("s_waitcnt vmcnt(0)" ::: "memory");
    __builtin_amdgcn_s_barrier();

    // P -> bf16 A-frags and PV (V from LDS)
#pragma unroll
    for (int c = 0; c < 4; ++c) {
      const int cb = c >> 1, r0 = 8 * (c & 1);
      unsigned A01 = pack2(sa[cb][r0],     sa[cb][r0 + 1]);
      unsigned A23 = pack2(sa[cb][r0 + 2], sa[cb][r0 + 3]);
      unsigned B01 = pack2(sa[cb][r0 + 4], sa[cb][r0 + 5]);
      unsigned B23 = pack2(sa[cb][r0 + 6], sa[cb][r0 + 7]);
      unsigned s1 = __shfl_xor(h ? A01 : B01, 32);
      unsigned s2 = __shfl_xor(h ? A23 : B23, 32);
      int4 wv;
      wv.x = (int)(h ? s1 : A01);
      wv.y = (int)(h ? s2 : A23);
      wv.z = (int)(h ? B01 : s1);
      wv.w = (int)(h ? B23 : s2);
      bf16x8 pa = *reinterpret_cast<bf16x8*>(&wv);
#pragma unroll
      for (int d0 = 0; d0 < 4; ++d0) {
        int vr = d0 * 32 + lq;
        bf16x8 vv = *reinterpret_cast<const bf16x8*>(
            Vl + vr * 128 + ((c * 32 + h * 16) ^ ((vr & 7) << 4)));
        oacc[d0] = __builtin_amdgcn_mfma_f32_32x32x16_bf16(pa, vv, oacc[d0], 0, 0, 0);
      }
    }
  }

  float invl = 1.0f / ll;
#pragma unroll
  for (int r = 0; r < 16; ++r) {
    int qoff = (r & 3) + 8 * (r >> 2) + 4 * h;
    float ir = __shfl(invl, qoff);
    int qrow = q0 + qoff;
#pragma unroll
    for (int d0 = 0; d0 < 4; ++d0)
      ob[((size_t)bbb * SEQ + qrow) * DMODEL + hh * HD + d0 * 32 + lq] =
          __float2bfloat16(oacc[d0][r] * ir);
  }
}

// ---------- launch ----------
extern "C" void kernel_launch(void* const* d_in, const int* in_sizes, int n_in,
                              void* d_out, int out_size, void* d_ws, size_t ws_size,
                              hipStream_t stream) {
  const float* x   = (const float*)d_in[0];
  const int* seq_lens   = (const int*)d_in[1];
  const int* grid_sizes = (const int*)d_in[2];
  const float* fc  = (const float*)d_in[3];
  const float* fs  = (const float*)d_in[4];
  const float* Wq  = (const float*)d_in[5];
  const float* bq  = (const float*)d_in[6];
  const float* Wk  = (const float*)d_in[7];
  const float* bk  = (const float*)d_in[8];
  const float* Wv  = (const float*)d_in[9];
  const float* bv  = (const float*)d_in[10];
  const float* Wo  = (const float*)d_in[11];
  const float* bo  = (const float*)d_in[12];
  const float* gq  = (const float*)d_in[13];
  const float* gk  = (const float*)d_in[14];
  const int* nmod  = (const int*)d_in[15];
  float* out = (float*)d_out;

  char* ws = (char*)d_ws;
  __hip_bfloat16* xb   = (__hip_bfloat16*)(ws + 0);           // [7168][1536]
  __hip_bfloat16* wb   = (__hip_bfloat16*)(ws + 22020096);    // [4608][1536]
  __hip_bfloat16* wob  = (__hip_bfloat16*)(ws + 36175872);    // [1536][1536]
  __hip_bfloat16* qbuf = (__hip_bfloat16*)(ws + 40894464);    // [48][1792][128]
  __hip_bfloat16* kbuf = (__hip_bfloat16*)(ws + 62914560);    // [48][1792][128]
  __hip_bfloat16* vtb  = (__hip_bfloat16*)(ws + 84934656);    // [48][128][1792]
  __hip_bfloat16* ob   = xb;                                  // O reuses xb region

  cast_all_kernel<<<(5111808 + 255) / 256, 256, 0, stream>>>(x, Wq, Wk, Wv, Wo, xb, wb, wob);

  // QKV: M=7168 (28 tiles) x N=4608 (18 tiles) -> 504 = 8*63
  gemm8<0><<<504, 512, 0, stream>>>(xb, wb, 18, 63, bq, bk, bv,
                                    qbuf, kbuf, vtb, nullptr, nullptr);
  rmsrope_kernel<<<7168, 256, 0, stream>>>(qbuf, kbuf, gq, gk, fc, fs, grid_sizes, nmod);
  attn_kernel<<<672, 256, 0, stream>>>(qbuf, kbuf, vtb, seq_lens, ob);
  // out-proj: M=7168 (28) x N=1536 (6 tiles) -> 168 = 8*21
  gemm8<1><<<168, 512, 0, stream>>>(ob, wob, 6, 21, nullptr, nullptr, nullptr,
                                    nullptr, nullptr, nullptr, bo, out);
}